// Round 16
// baseline (295.801 us; speedup 1.0000x reference)
//
#include <hip/hip_runtime.h>
#include <hip/hip_bf16.h>

#define NPX 50176
#define SCALE 0.17677669529663687f

typedef __attribute__((ext_vector_type(8))) short short8;
typedef __attribute__((ext_vector_type(4))) float floatx4;
using u16x8 = __attribute__((ext_vector_type(8))) unsigned short;

static __device__ __forceinline__ float bf2f(unsigned short u) {
  union { unsigned int i; float f; } c; c.i = ((unsigned int)u) << 16; return c.f;
}
static __device__ __forceinline__ unsigned short f2bf(float f) {
  union { float f; unsigned int i; } c; c.f = f;
  unsigned int u = c.i;
  u += 0x7fffu + ((u >> 16) & 1u);
  return (unsigned short)(u >> 16);
}

static __device__ __forceinline__ void gl_lds16(const unsigned short* g, unsigned short* l) {
  __builtin_amdgcn_global_load_lds(
      (const __attribute__((address_space(1))) void*)g,
      (__attribute__((address_space(3))) void*)l, 16, 0, 0);
}

// stage a 128x32 bf16 tile (row stride ldK elems) into linear LDS [128][32] (4096 u16)
static __device__ __forceinline__ void stage128x32(const unsigned short* g, int ldK,
                                                   unsigned short* lds, int tid) {
  const int wv = tid >> 6, lane = tid & 63;
#pragma unroll
  for (int i = 0; i < 2; ++i) {
    const int ci = i * 4 + wv;
    const int row = ci * 16 + (lane >> 2);
    const int col = (lane & 3) * 8;
    gl_lds16(g + (size_t)row * ldK + col, lds + ci * 512);
  }
}

// stage a 64x32 bf16 tile into linear LDS [64][32] (2048 u16); 1 granule/thread
static __device__ __forceinline__ void stage64x32(const unsigned short* g, int ldK,
                                                  unsigned short* lds, int tid) {
  const int row = tid >> 2;
  const int col = (tid & 3) * 8;
  gl_lds16(g + (size_t)row * ldK + col, lds + tid * 8);
}

// ---------------- converters / packers ----------------
__global__ __launch_bounds__(256) void k_cvt(const float* __restrict__ src,
                                             unsigned short* __restrict__ dst, int n8) {
  int i = blockIdx.x * 256 + threadIdx.x;
  const int stride = gridDim.x * 256;
  for (; i < n8; i += stride) {
    float4 f0 = *(const float4*)(src + (size_t)i * 8);
    float4 f1 = *(const float4*)(src + (size_t)i * 8 + 4);
    u16x8 o;
    o[0] = f2bf(f0.x); o[1] = f2bf(f0.y); o[2] = f2bf(f0.z); o[3] = f2bf(f0.w);
    o[4] = f2bf(f1.x); o[5] = f2bf(f1.y); o[6] = f2bf(f1.z); o[7] = f2bf(f1.w);
    *(u16x8*)(dst + (size_t)i * 8) = o;
  }
}

// fragment-pack a [ncols x 384] f32 row-major matrix into [g][s][lane][8] bf16
__global__ __launch_bounds__(256) void k_wfrag(const float* __restrict__ w,
                                               unsigned short* __restrict__ dst, int ntot) {
  int idx = blockIdx.x * 256 + threadIdx.x;
  if (idx < ntot) {
    int e = idx & 7;
    int lane = (idx >> 3) & 63;
    int s = (idx >> 9) % 12;
    int g = (idx >> 9) / 12;
    int col = g * 16 + (lane & 15);
    int k = s * 32 + (lane >> 4) * 8 + e;
    dst[idx] = f2bf(w[(size_t)col * 384 + k]);
  }
}

// fragment-pack w_post into hi/lo split: dst[h][g 24][s 12][lane][8]
__global__ __launch_bounds__(256) void k_wpostf(const float* __restrict__ w,
                                                unsigned short* __restrict__ dst) {
  int idx = blockIdx.x * 256 + threadIdx.x;  // 2*24*12*512 = 294912
  if (idx < 294912) {
    int e = idx & 7;
    int lane = (idx >> 3) & 63;
    int s = (idx >> 9) % 12;
    int gh = (idx >> 9) / 12;   // 0..47
    int g = gh % 24, h = gh / 24;
    int col = g * 16 + (lane & 15);
    int k = s * 32 + (lane >> 4) * 8 + e;
    float f = w[(size_t)col * 384 + k];
    unsigned short hi = f2bf(f);
    dst[idx] = (h == 0) ? hi : f2bf(f - bf2f(hi));
  }
}

// w1mp[pairg 16][s 13][lane 64][i 8] bf16, exact 16x16x32 MFMA B-fragment order.
__global__ __launch_bounds__(256) void k_w1mpack(const float* __restrict__ w1,
                                                 unsigned short* __restrict__ w1mp) {
  int idx = blockIdx.x * 256 + threadIdx.x;  // 16*13*64*8 = 106496
  if (idx < 106496) {
    int i = idx & 7;
    int lane = (idx >> 3) & 63;
    int ps = idx >> 9;          // pairg*13 + s
    int s = ps % 13;
    int pairg = ps / 13;
    int n = lane & 15, qq = lane >> 4;
    int k = s * 32 + qq * 8 + i;
    int t = k >> 4, ich = k & 15;
    int o = pairg * 16 + n;
    float v = 0.f;
    if (t < 25 && (ich >> 3) == (n >> 3))
      v = w1[o * 200 + (ich & 7) * 25 + t];
    w1mp[idx] = f2bf(v);
  }
}

// w2f[g 19][s 8][lane][8] bf16, MFMA B-fragment order (cols 300..303 zero)
__global__ __launch_bounds__(256) void k_w2frag(const float* __restrict__ w2,
                                                unsigned short* __restrict__ w2f) {
  int idx = blockIdx.x * 256 + threadIdx.x;  // 19*8*512 = 77824
  if (idx < 77824) {
    int e = idx & 7;
    int lane = (idx >> 3) & 63;
    int s = (idx >> 9) & 7;
    int g = idx >> 12;
    int col = g * 16 + (lane & 15);
    int k = s * 32 + (lane >> 4) * 8 + e;
    w2f[idx] = (col < 300) ? f2bf(w2[(size_t)col * 256 + k]) : (unsigned short)0;
  }
}

// ggp[chunk 3][kk 25][ol 16][q 4][i 4] f32 — the EXACT swizzled LDS image each
// k_elsa chunk needs (phys granule q holds logical L = q ^ ((ol>>1)&3)).
__global__ __launch_bounds__(256) void k_ggpack(const float* __restrict__ gh,
                                                float* __restrict__ ggp) {
  int idx = blockIdx.x * 256 + threadIdx.x;  // 3*25*16*16 = 19200
  if (idx < 19200) {
    int i = idx & 3;
    int q = (idx >> 2) & 3;
    int ol = (idx >> 4) & 15;
    int kk = (idx >> 8) % 25;
    int chunk = idx / 6400;
    int swz = (ol >> 1) & 3;
    int L = q ^ swz;
    int og = chunk * 16 + ol;
    ggp[idx] = gh[(L >> 1) * 9600 + (og * 8 + (L & 1) * 4 + i) * 25 + kk];
  }
}

// ---------------- Kernel A1: pre GEMM q&k + hadamard (B frags from L2) ----------------
__global__ __launch_bounds__(256) void k_pre_qk(const unsigned short* __restrict__ xb,
                                                const unsigned short* __restrict__ wpbf,
                                                unsigned short* __restrict__ had) {
  __shared__ unsigned short sA[2][4096];
  const int tid = threadIdx.x;
  const int m0 = blockIdx.x * 128;
  const int yb = blockIdx.y;            // 0..1
  const int lane = tid & 63, wv = tid >> 6;
  const int wr = wv >> 1, wc = wv & 1;

  const floatx4 fz = {0.f, 0.f, 0.f, 0.f};
  floatx4 acc0[4][4], acc1[4][4];
#pragma unroll
  for (int i = 0; i < 4; ++i)
#pragma unroll
    for (int j = 0; j < 4; ++j) { acc0[i][j] = fz; acc1[i][j] = fz; }

  stage128x32(xb + (size_t)m0 * 384, 384, sA[0], tid);
  const unsigned short* bbase = wpbf + (size_t)(yb * 8 + wc * 4) * 6144 + lane * 8;

  int cur = 0;
#pragma unroll 1
  for (int s = 0; s < 12; ++s) {
    short8 b0[4], b1[4];
#pragma unroll
    for (int nf = 0; nf < 4; ++nf) {
      b0[nf] = *(const short8*)(bbase + (size_t)s * 512 + nf * 6144);
      b1[nf] = *(const short8*)(bbase + (size_t)s * 512 + nf * 6144 + 98304);
    }
    __syncthreads();
    if (s < 11) stage128x32(xb + (size_t)m0 * 384 + (s + 1) * 32, 384, sA[cur ^ 1], tid);
    short8 a[4];
#pragma unroll
    for (int mf = 0; mf < 4; ++mf)
      a[mf] = *(const short8*)&sA[cur][(wr * 64 + mf * 16 + (lane & 15)) * 32 + (lane >> 4) * 8];
#pragma unroll
    for (int mf = 0; mf < 4; ++mf)
#pragma unroll
      for (int nf = 0; nf < 4; ++nf) {
        acc0[mf][nf] = __builtin_amdgcn_mfma_f32_16x16x32_bf16(a[mf], b0[nf], acc0[mf][nf], 0, 0, 0);
        acc1[mf][nf] = __builtin_amdgcn_mfma_f32_16x16x32_bf16(a[mf], b1[nf], acc1[mf][nf], 0, 0, 0);
      }
    cur ^= 1;
  }

  const int colbase = yb * 128 + wc * 64;
#pragma unroll
  for (int mf = 0; mf < 4; ++mf)
#pragma unroll
    for (int nf = 0; nf < 4; ++nf) {
      const int col = colbase + nf * 16 + (lane & 15);
#pragma unroll
      for (int j = 0; j < 4; ++j) {
        const int row = m0 + wr * 64 + mf * 16 + (lane >> 4) * 4 + j;
        had[(size_t)row * 256 + col] = f2bf(acc0[mf][nf][j] * acc1[mf][nf][j] * SCALE);
      }
    }
}

// ---------------- Kernel A2: pre GEMM v (B frags from L2) ----------------
__global__ __launch_bounds__(256) void k_pre_v(const unsigned short* __restrict__ xb,
                                               const unsigned short* __restrict__ wpbf,
                                               unsigned short* __restrict__ vout) {
  __shared__ unsigned short sA[2][4096];
  const int tid = threadIdx.x;
  const int m0 = blockIdx.x * 128;
  const int yb = blockIdx.y;            // 0..2
  const int lane = tid & 63, wv = tid >> 6;
  const int wr = wv >> 1, wc = wv & 1;

  const floatx4 fz = {0.f, 0.f, 0.f, 0.f};
  floatx4 acc[4][4];
#pragma unroll
  for (int i = 0; i < 4; ++i)
#pragma unroll
    for (int j = 0; j < 4; ++j) acc[i][j] = fz;

  stage128x32(xb + (size_t)m0 * 384, 384, sA[0], tid);
  const unsigned short* bbase = wpbf + (size_t)(32 + yb * 8 + wc * 4) * 6144 + lane * 8;

  int cur = 0;
#pragma unroll 1
  for (int s = 0; s < 12; ++s) {
    short8 b[4];
#pragma unroll
    for (int nf = 0; nf < 4; ++nf)
      b[nf] = *(const short8*)(bbase + (size_t)s * 512 + nf * 6144);
    __syncthreads();
    if (s < 11) stage128x32(xb + (size_t)m0 * 384 + (s + 1) * 32, 384, sA[cur ^ 1], tid);
    short8 a[4];
#pragma unroll
    for (int mf = 0; mf < 4; ++mf)
      a[mf] = *(const short8*)&sA[cur][(wr * 64 + mf * 16 + (lane & 15)) * 32 + (lane >> 4) * 8];
#pragma unroll
    for (int mf = 0; mf < 4; ++mf)
#pragma unroll
      for (int nf = 0; nf < 4; ++nf)
        acc[mf][nf] = __builtin_amdgcn_mfma_f32_16x16x32_bf16(a[mf], b[nf], acc[mf][nf], 0, 0, 0);
    cur ^= 1;
  }

  const int colbase = yb * 128 + wc * 64;
#pragma unroll
  for (int mf = 0; mf < 4; ++mf)
#pragma unroll
    for (int nf = 0; nf < 4; ++nf) {
      const int col = colbase + nf * 16 + (lane & 15);
#pragma unroll
      for (int j = 0; j < 4; ++j) {
        const int row = m0 + wr * 64 + mf * 16 + (lane >> 4) * 4 + j;
        vout[(size_t)row * 384 + col] = f2bf(acc[mf][nf][j]);
      }
    }
}

// ---------------- Kernel B1: grouped 5x5 conv + GELU, MFMA version ----------------
__global__ __launch_bounds__(256) void k_conv_mfma(const unsigned short* __restrict__ had,
                                                   const unsigned short* __restrict__ w1mp,
                                                   const float* __restrict__ b1,
                                                   unsigned short* __restrict__ hm) {
  __shared__ unsigned short halo[8 * 288 * 8];  // 36,864 B
  const int tid = threadIdx.x;
  const int lane = tid & 63, wv = tid >> 6;
  const int bimg = blockIdx.x / 49;
  const int t49 = blockIdx.x % 49;
  const int y0 = (t49 / 7) * 8, x0 = (t49 % 7) * 8;
  const int half = blockIdx.y;
  const int c0 = half * 128;

  for (int ii = tid; ii < 2304; ii += 256) {
    const int g16 = ii & 15;       // pair*2 + h
    const int pyx = ii >> 4;       // 0..143
    const int py = pyx / 12, px = pyx % 12;
    const int gy = y0 + py - 2, gx = x0 + px - 2;
    uint4 val = make_uint4(0u, 0u, 0u, 0u);
    if (gy >= 0 && gy < 56 && gx >= 0 && gx < 56)
      val = *(const uint4*)(had + ((size_t)(bimg * 56 + gy) * 56 + gx) * 256 + c0 + g16 * 8);
    *(uint4*)&halo[(size_t)(((g16 >> 1) * 288 + (g16 & 1) * 144 + pyx)) * 8] = val;
  }
  __syncthreads();

  const int r = lane & 15;
  const int q = lane >> 4;
  const int h = q & 1, qh = q >> 1;

  const unsigned short* abase =
      &halo[(size_t)((wv * 2) * 288 + h * 144 + (r >> 3) * 12 + (r & 7)) * 8];
  const unsigned short* wq =
      w1mp + (size_t)((half * 8 + wv * 2) * 13) * 512 + lane * 8;

  const float bs0 = b1[(half * 8 + wv * 2) * 16 + r];
  const float bs1 = b1[(half * 8 + wv * 2 + 1) * 16 + r];

  floatx4 acc[2][4];
#pragma unroll
  for (int mf = 0; mf < 4; ++mf) {
    acc[0][mf] = (floatx4){bs0, bs0, bs0, bs0};
    acc[1][mf] = (floatx4){bs1, bs1, bs1, bs1};
  }

#pragma unroll
  for (int s = 0; s < 13; ++s) {
    const int t0 = 2 * s;
    const int t1 = (t0 + 1 > 24) ? 24 : t0 + 1;
    const int o0 = (t0 / 5) * 12 + (t0 % 5);
    const int o1 = (t1 / 5) * 12 + (t1 % 5);
    const unsigned short* ap = abase + (size_t)(qh ? o1 : o0) * 8;
    const short8 bf0 = *(const short8*)(wq + (size_t)s * 512);
    const short8 bf1 = *(const short8*)(wq + (size_t)(13 + s) * 512);
#pragma unroll
    for (int mf = 0; mf < 4; ++mf) {
      const short8 a0 = *(const short8*)(ap + mf * 192);
      acc[0][mf] = __builtin_amdgcn_mfma_f32_16x16x32_bf16(a0, bf0, acc[0][mf], 0, 0, 0);
    }
#pragma unroll
    for (int mf = 0; mf < 4; ++mf) {
      const short8 a1 = *(const short8*)(ap + 2304 + mf * 192);
      acc[1][mf] = __builtin_amdgcn_mfma_f32_16x16x32_bf16(a1, bf1, acc[1][mf], 0, 0, 0);
    }
  }

#pragma unroll
  for (int pp = 0; pp < 2; ++pp) {
    const int o = (half * 8 + wv * 2 + pp) * 16 + r;
#pragma unroll
    for (int mf = 0; mf < 4; ++mf)
#pragma unroll
      for (int j = 0; j < 4; ++j) {
        const int pix = mf * 16 + q * 4 + j;
        const int pyl = pix >> 3, pxl = pix & 7;
        const size_t gp = (size_t)(bimg * 56 + y0 + pyl) * 56 + (x0 + pxl);
        const float vv = acc[pp][mf][j];
        const float g = 0.5f * vv * (1.0f + erff(vv * 0.70710678118654752f));
        hm[gp * 256 + o] = f2bf(g);
      }
  }
}

// ---------------- Kernel B2: 1x1 GEMM + fused softmax, 64-px blocks ----------------
__global__ __launch_bounds__(256) void k_1x1s(const unsigned short* __restrict__ hm,
                                              const unsigned short* __restrict__ w2f,
                                              const float* __restrict__ b2,
                                              unsigned short* __restrict__ attn) {
  __shared__ unsigned short sA[2][2048];
  __shared__ unsigned short sw[4][16][312];
  const int tid = threadIdx.x;
  const int lane = tid & 63, wv = tid >> 6;
  const int m0 = blockIdx.x * 64;

  const floatx4 fz = {0.f, 0.f, 0.f, 0.f};
  floatx4 acc[19];
#pragma unroll
  for (int nf = 0; nf < 19; ++nf) acc[nf] = fz;

  stage64x32(hm + (size_t)m0 * 256, 256, sA[0], tid);
  const unsigned short* bbase = w2f + lane * 8;
  int cur = 0;
#pragma unroll 1
  for (int s = 0; s < 8; ++s) {
    short8 b[19];
#pragma unroll
    for (int nf = 0; nf < 19; ++nf)
      b[nf] = *(const short8*)(bbase + (size_t)(nf * 8 + s) * 512);
    __syncthreads();
    if (s < 7) stage64x32(hm + (size_t)m0 * 256 + (s + 1) * 32, 256, sA[cur ^ 1], tid);
    const short8 a = *(const short8*)&sA[cur][(wv * 16 + (lane & 15)) * 32 + (lane >> 4) * 8];
#pragma unroll
    for (int nf = 0; nf < 19; ++nf)
      acc[nf] = __builtin_amdgcn_mfma_f32_16x16x32_bf16(a, b[nf], acc[nf], 0, 0, 0);
    cur ^= 1;
  }
  __syncthreads();

#pragma unroll
  for (int nf = 0; nf < 19; ++nf) {
    const int col = nf * 16 + (lane & 15);
    const float bias = (col < 300) ? b2[col] : 0.f;
#pragma unroll
    for (int j = 0; j < 4; ++j) {
      const int row = (lane >> 4) * 4 + j;
      sw[wv][row][col] = f2bf(acc[nf][j] + bias);
    }
  }
  __syncthreads();

#pragma unroll
  for (int t = 0; t < 3; ++t) {
    const int tt = t * 64 + lane;
    const int px = tt & 15, g = tt >> 4;
    unsigned short* srow = &sw[wv][px][g * 25];
    float a2[25];
#pragma unroll
    for (int kk = 0; kk < 25; ++kk) a2[kk] = bf2f(srow[kk]);
    float m = a2[0];
#pragma unroll
    for (int kk = 1; kk < 25; ++kk) m = fmaxf(m, a2[kk]);
    float s = 0.f;
#pragma unroll
    for (int kk = 0; kk < 25; ++kk) { a2[kk] = __expf(a2[kk] - m); s += a2[kk]; }
    const float rr = 1.0f / s;
#pragma unroll
    for (int kk = 0; kk < 25; ++kk) srow[kk] = f2bf(a2[kk] * rr);
  }
  __syncthreads();

  const unsigned short* swl = &sw[0][0][0];
  for (int i = tid; i < 4800; i += 256) {
    const int r = i / 75, c = i % 75;
    const uint2 val = *(const uint2*)(swl + (size_t)r * 312 + c * 4);
    *(uint2*)(attn + (size_t)(m0 + r) * 300 + c * 4) = val;
  }
}

// ---------------- Kernel C: ELSA aggregation v9 (P=4 px/thread) ----------------
// 512 threads = 16 octets x 32 quads; block = 128 px, grid (392, 3).
// The 4 b128 gm/ga reads per tap are shared by 4 pixels (was 2) -> per-pixel
// table-LDS halves; 8 v-loads per tap-row cover 4 pixels (2/px, was 3/px).
__global__ __launch_bounds__(512) void k_elsa(const unsigned short* __restrict__ v,
                                              const unsigned short* __restrict__ attn,
                                              const float* __restrict__ ggp,
                                              unsigned short* __restrict__ outp) {
  __shared__ float sGG[25 * 16 * 16];       // 25,600 B
  __shared__ unsigned short sAt[128][104];  // 26,624 B
  const int tid = threadIdx.x;
  const int chunk = blockIdx.y;
  const int pb = blockIdx.x * 128;

  {
    const float4* src = (const float4*)(ggp + (size_t)chunk * 6400);
    float4* dst = (float4*)sGG;
    for (int j = tid; j < 1600; j += 512) dst[j] = src[j];
  }
  // stage attn: 128 rows x 100 u16 (this chunk's 4 heads), dense 8B loads
  for (int j = tid; j < 3200; j += 512) {
    const int r = j / 25, c = j % 25;
    const uint2 val = *(const uint2*)(attn + (size_t)(pb + r) * 300 + chunk * 100 + c * 4);
    *(uint2*)&sAt[r][c * 4] = val;
  }
  __syncthreads();

  const int ol = tid & 15;
  const int og = chunk * 16 + ol;
  const int pxi = tid >> 4;           // 0..31
  const int gl = ol >> 2;             // head within chunk
  const int swz = (ol >> 1) & 3;
  const int p0 = pb + pxi * 4;        // 56%4==0: quad never straddles a row
  const int xp = p0 % 56;
  const int yp = (p0 / 56) % 56;
  const int pxl = pxi * 4;

  const unsigned short* __restrict__ vb = v + ((size_t)p0 - 114) * 384 + og * 8;

  float acc[4][8];
#pragma unroll
  for (int px = 0; px < 4; ++px)
#pragma unroll
    for (int i = 0; i < 8; ++i) acc[px][i] = 0.f;

  const u16x8 hz = {0, 0, 0, 0, 0, 0, 0, 0};

#pragma unroll 1
  for (int dy = 0; dy < 5; ++dy) {
    const bool rowok = (unsigned)(yp + dy - 2) < 56u;
    u16x8 hv[8];
#pragma unroll
    for (int j = 0; j < 8; ++j) {
      const bool ok = rowok && ((unsigned)(xp - 2 + j) < 56u);
      hv[j] = ok ? *(const u16x8*)(vb + ((size_t)dy * 56 + j) * 384) : hz;
    }
#pragma unroll
    for (int t = 0; t < 5; ++t) {
      const int kk = dy * 5 + t;
      const float* gg = &sGG[(kk * 16 + ol) << 4];
      const float4 gm0 = *(const float4*)(gg + ((0 ^ swz) << 2));
      const float4 gm1 = *(const float4*)(gg + ((1 ^ swz) << 2));
      const float4 ga0 = *(const float4*)(gg + ((2 ^ swz) << 2));
      const float4 ga1 = *(const float4*)(gg + ((3 ^ swz) << 2));
#pragma unroll
      for (int px = 0; px < 4; ++px) {
        const float a = bf2f(sAt[pxl + px][gl * 25 + kk]);
        const u16x8 hvv = hv[t + px];
        acc[px][0] = fmaf(bf2f(hvv[0]), fmaf(gm0.x, a, ga0.x), acc[px][0]);
        acc[px][1] = fmaf(bf2f(hvv[1]), fmaf(gm0.y, a, ga0.y), acc[px][1]);
        acc[px][2] = fmaf(bf2f(hvv[2]), fmaf(gm0.z, a, ga0.z), acc[px][2]);
        acc[px][3] = fmaf(bf2f(hvv[3]), fmaf(gm0.w, a, ga0.w), acc[px][3]);
        acc[px][4] = fmaf(bf2f(hvv[4]), fmaf(gm1.x, a, ga1.x), acc[px][4]);
        acc[px][5] = fmaf(bf2f(hvv[5]), fmaf(gm1.y, a, ga1.y), acc[px][5]);
        acc[px][6] = fmaf(bf2f(hvv[6]), fmaf(gm1.z, a, ga1.z), acc[px][6]);
        acc[px][7] = fmaf(bf2f(hvv[7]), fmaf(gm1.w, a, ga1.w), acc[px][7]);
      }
    }
  }

#pragma unroll
  for (int px = 0; px < 4; ++px) {
    u16x8 ov;
#pragma unroll
    for (int i = 0; i < 8; ++i) ov[i] = f2bf(acc[px][i]);
    *(u16x8*)(outp + (size_t)(p0 + px) * 384 + og * 8) = ov;
  }
}

// ---------------- Kernel D: post GEMM (hi/lo B frags from L2) ----------------
__global__ __launch_bounds__(256) void k_post_mfma(const unsigned short* __restrict__ outp,
                                                   const unsigned short* __restrict__ wpostf,
                                                   const float* __restrict__ b_post,
                                                   float* __restrict__ out) {
  __shared__ unsigned short sA[2][4096];
  const int tid = threadIdx.x;
  const int m0 = blockIdx.x * 128;
  const int yb = blockIdx.y;            // 0..2
  const int lane = tid & 63, wv = tid >> 6;
  const int wr = wv >> 1, wc = wv & 1;

  const floatx4 fz = {0.f, 0.f, 0.f, 0.f};
  floatx4 acc[4][4];
#pragma unroll
  for (int i = 0; i < 4; ++i)
#pragma unroll
    for (int j = 0; j < 4; ++j) acc[i][j] = fz;

  stage128x32(outp + (size_t)m0 * 384, 384, sA[0], tid);
  const unsigned short* bbase = wpostf + (size_t)(yb * 8 + wc * 4) * 6144 + lane * 8;

  int cur = 0;
#pragma unroll 1
  for (int s = 0; s < 12; ++s) {
    short8 bh[4], bl[4];
#pragma unroll
    for (int nf = 0; nf < 4; ++nf) {
      bh[nf] = *(const short8*)(bbase + (size_t)s * 512 + nf * 6144);
      bl[nf] = *(const short8*)(bbase + (size_t)s * 512 + nf * 6144 + 147456);
    }
    __syncthreads();
    if (s < 11) stage128x32(outp + (size_t)m0 * 384 + (s + 1) * 32, 384, sA[cur ^ 1], tid);
    short8 a[4];
#pragma unroll
    for (int mf = 0; mf < 4; ++mf)
      a[mf] = *(const short8*)&sA[cur][(wr * 64 + mf * 16 + (lane & 15)) * 32 + (lane >> 4) * 8];
#pragma unroll
    for (int mf = 0; mf < 4; ++mf)
#pragma unroll
      for (int nf = 0; nf < 4; ++nf) {
        acc[mf][nf] = __builtin_amdgcn_mfma_f32_16x16x32_bf16(a[mf], bh[nf], acc[mf][nf], 0, 0, 0);
        acc[mf][nf] = __builtin_amdgcn_mfma_f32_16x16x32_bf16(a[mf], bl[nf], acc[mf][nf], 0, 0, 0);
      }
    cur ^= 1;
  }

#pragma unroll
  for (int mf = 0; mf < 4; ++mf)
#pragma unroll
    for (int nf = 0; nf < 4; ++nf) {
      const int col = yb * 128 + wc * 64 + nf * 16 + (lane & 15);
      const float bias = b_post[col];
#pragma unroll
      for (int j = 0; j < 4; ++j) {
        const int row = m0 + wr * 64 + mf * 16 + (lane >> 4) * 4 + j;
        out[(size_t)row * 384 + col] = acc[mf][nf][j] + bias;
      }
    }
}

extern "C" void kernel_launch(void* const* d_in, const int* in_sizes, int n_in,
                              void* d_out, int out_size, void* d_ws, size_t ws_size,
                              hipStream_t stream) {
  const float* x      = (const float*)d_in[0];
  const float* w_pre  = (const float*)d_in[1];
  const float* w1     = (const float*)d_in[2];
  const float* b1     = (const float*)d_in[3];
  const float* w2     = (const float*)d_in[4];
  const float* b2     = (const float*)d_in[5];
  const float* gh     = (const float*)d_in[6];
  const float* w_post = (const float*)d_in[7];
  const float* b_post = (const float*)d_in[8];
  float* out = (float*)d_out;

  char* ws = (char*)d_ws;
  unsigned short* xb     = (unsigned short*)ws;
  unsigned short* hm     = (unsigned short*)ws;
  unsigned short* w1mp   = (unsigned short*)(ws + 25690112);
  unsigned short* w2f    = (unsigned short*)(ws + 25903104);    // 155,648 B
  unsigned short* outp   = (unsigned short*)ws;
  unsigned short* had    = (unsigned short*)(ws + 38535168);
  float*          ggp    = (float*)(ws + 38535168);             // reuses dead `had`
  unsigned short* v      = (unsigned short*)(ws + 64225280);
  unsigned short* attn   = (unsigned short*)(ws + 102760448);
  unsigned short* wpbf   = (unsigned short*)(ws + 132866048);   // 688,128 B (56 groups)
  unsigned short* wpostf = (unsigned short*)(ws + 133554176);   // 589,824 B (hi+lo)

  k_cvt<<<dim3(2048), dim3(256), 0, stream>>>(x, xb, 19267584 / 8);
  k_wfrag<<<dim3(1344), dim3(256), 0, stream>>>(w_pre, wpbf, 344064);
  k_wpostf<<<dim3(1152), dim3(256), 0, stream>>>(w_post, wpostf);

  k_pre_qk<<<dim3(392, 2), dim3(256), 0, stream>>>(xb, wpbf, had);
  k_pre_v<<<dim3(392, 3), dim3(256), 0, stream>>>(xb, wpbf, v);

  // xb dead now; pack small weights into R0 slack
  k_w1mpack<<<dim3(416), dim3(256), 0, stream>>>(w1, w1mp);
  k_w2frag<<<dim3(304), dim3(256), 0, stream>>>(w2, w2f);

  k_conv_mfma<<<dim3(784, 2), dim3(256), 0, stream>>>(had, w1mp, b1, hm);
  // had dead now; ggp reuses its storage (outside R0, so k_elsa's outp writes
  // cannot clobber it)
  k_ggpack<<<dim3(75), dim3(256), 0, stream>>>(gh, ggp);
  k_1x1s<<<dim3(784), dim3(256), 0, stream>>>(hm, w2f, b2, attn);
  k_elsa<<<dim3(392, 3), dim3(512), 0, stream>>>(v, attn, ggp, outp);
  k_post_mfma<<<dim3(392, 3), dim3(256), 0, stream>>>(outp, wpostf, b_post, out);
}

// Round 17
// 282.495 us; speedup vs baseline: 1.0471x; 1.0471x over previous
//
#include <hip/hip_runtime.h>
#include <hip/hip_bf16.h>

#define NPX 50176
#define SCALE 0.17677669529663687f

typedef __attribute__((ext_vector_type(8))) short short8;
typedef __attribute__((ext_vector_type(4))) float floatx4;
using u16x8 = __attribute__((ext_vector_type(8))) unsigned short;

static __device__ __forceinline__ float bf2f(unsigned short u) {
  union { unsigned int i; float f; } c; c.i = ((unsigned int)u) << 16; return c.f;
}
static __device__ __forceinline__ unsigned short f2bf(float f) {
  union { float f; unsigned int i; } c; c.f = f;
  unsigned int u = c.i;
  u += 0x7fffu + ((u >> 16) & 1u);
  return (unsigned short)(u >> 16);
}

static __device__ __forceinline__ void gl_lds16(const unsigned short* g, unsigned short* l) {
  __builtin_amdgcn_global_load_lds(
      (const __attribute__((address_space(1))) void*)g,
      (__attribute__((address_space(3))) void*)l, 16, 0, 0);
}

// stage a 128x32 bf16 tile (row stride ldK elems) into linear LDS [128][32] (4096 u16)
static __device__ __forceinline__ void stage128x32(const unsigned short* g, int ldK,
                                                   unsigned short* lds, int tid) {
  const int wv = tid >> 6, lane = tid & 63;
#pragma unroll
  for (int i = 0; i < 2; ++i) {
    const int ci = i * 4 + wv;
    const int row = ci * 16 + (lane >> 2);
    const int col = (lane & 3) * 8;
    gl_lds16(g + (size_t)row * ldK + col, lds + ci * 512);
  }
}

// stage a 64x32 bf16 tile into linear LDS [64][32] (2048 u16); 1 granule/thread
static __device__ __forceinline__ void stage64x32(const unsigned short* g, int ldK,
                                                  unsigned short* lds, int tid) {
  const int row = tid >> 2;
  const int col = (tid & 3) * 8;
  gl_lds16(g + (size_t)row * ldK + col, lds + tid * 8);
}

// ---------------- converters / packers ----------------
__global__ __launch_bounds__(256) void k_cvt(const float* __restrict__ src,
                                             unsigned short* __restrict__ dst, int n8) {
  int i = blockIdx.x * 256 + threadIdx.x;
  const int stride = gridDim.x * 256;
  for (; i < n8; i += stride) {
    float4 f0 = *(const float4*)(src + (size_t)i * 8);
    float4 f1 = *(const float4*)(src + (size_t)i * 8 + 4);
    u16x8 o;
    o[0] = f2bf(f0.x); o[1] = f2bf(f0.y); o[2] = f2bf(f0.z); o[3] = f2bf(f0.w);
    o[4] = f2bf(f1.x); o[5] = f2bf(f1.y); o[6] = f2bf(f1.z); o[7] = f2bf(f1.w);
    *(u16x8*)(dst + (size_t)i * 8) = o;
  }
}

// fragment-pack a [ncols x 384] f32 row-major matrix into [g][s][lane][8] bf16
__global__ __launch_bounds__(256) void k_wfrag(const float* __restrict__ w,
                                               unsigned short* __restrict__ dst, int ntot) {
  int idx = blockIdx.x * 256 + threadIdx.x;
  if (idx < ntot) {
    int e = idx & 7;
    int lane = (idx >> 3) & 63;
    int s = (idx >> 9) % 12;
    int g = (idx >> 9) / 12;
    int col = g * 16 + (lane & 15);
    int k = s * 32 + (lane >> 4) * 8 + e;
    dst[idx] = f2bf(w[(size_t)col * 384 + k]);
  }
}

// fragment-pack w_post into hi/lo split: dst[h][g 24][s 12][lane][8]
__global__ __launch_bounds__(256) void k_wpostf(const float* __restrict__ w,
                                                unsigned short* __restrict__ dst) {
  int idx = blockIdx.x * 256 + threadIdx.x;  // 2*24*12*512 = 294912
  if (idx < 294912) {
    int e = idx & 7;
    int lane = (idx >> 3) & 63;
    int s = (idx >> 9) % 12;
    int gh = (idx >> 9) / 12;   // 0..47
    int g = gh % 24, h = gh / 24;
    int col = g * 16 + (lane & 15);
    int k = s * 32 + (lane >> 4) * 8 + e;
    float f = w[(size_t)col * 384 + k];
    unsigned short hi = f2bf(f);
    dst[idx] = (h == 0) ? hi : f2bf(f - bf2f(hi));
  }
}

// w1mp[pairg 16][s 13][lane 64][i 8] bf16, exact 16x16x32 MFMA B-fragment order.
__global__ __launch_bounds__(256) void k_w1mpack(const float* __restrict__ w1,
                                                 unsigned short* __restrict__ w1mp) {
  int idx = blockIdx.x * 256 + threadIdx.x;  // 16*13*64*8 = 106496
  if (idx < 106496) {
    int i = idx & 7;
    int lane = (idx >> 3) & 63;
    int ps = idx >> 9;          // pairg*13 + s
    int s = ps % 13;
    int pairg = ps / 13;
    int n = lane & 15, qq = lane >> 4;
    int k = s * 32 + qq * 8 + i;
    int t = k >> 4, ich = k & 15;
    int o = pairg * 16 + n;
    float v = 0.f;
    if (t < 25 && (ich >> 3) == (n >> 3))
      v = w1[o * 200 + (ich & 7) * 25 + t];
    w1mp[idx] = f2bf(v);
  }
}

// w2f[g 19][s 8][lane][8] bf16, MFMA B-fragment order (cols 300..303 zero)
__global__ __launch_bounds__(256) void k_w2frag(const float* __restrict__ w2,
                                                unsigned short* __restrict__ w2f) {
  int idx = blockIdx.x * 256 + threadIdx.x;  // 19*8*512 = 77824
  if (idx < 77824) {
    int e = idx & 7;
    int lane = (idx >> 3) & 63;
    int s = (idx >> 9) & 7;
    int g = idx >> 12;
    int col = g * 16 + (lane & 15);
    int k = s * 32 + (lane >> 4) * 8 + e;
    w2f[idx] = (col < 300) ? f2bf(w2[(size_t)col * 256 + k]) : (unsigned short)0;
  }
}

// ggp[chunk 3][kk 25][ol 16][q 4][i 4] f32 — the EXACT swizzled LDS image each
// k_elsa chunk needs (phys granule q holds logical L = q ^ ((ol>>1)&3)).
__global__ __launch_bounds__(256) void k_ggpack(const float* __restrict__ gh,
                                                float* __restrict__ ggp) {
  int idx = blockIdx.x * 256 + threadIdx.x;  // 3*25*16*16 = 19200
  if (idx < 19200) {
    int i = idx & 3;
    int q = (idx >> 2) & 3;
    int ol = (idx >> 4) & 15;
    int kk = (idx >> 8) % 25;
    int chunk = idx / 6400;
    int swz = (ol >> 1) & 3;
    int L = q ^ swz;
    int og = chunk * 16 + ol;
    ggp[idx] = gh[(L >> 1) * 9600 + (og * 8 + (L & 1) * 4 + i) * 25 + kk];
  }
}

// ---------------- Kernel A1: pre GEMM q&k + hadamard (B frags from L2) ----------------
__global__ __launch_bounds__(256) void k_pre_qk(const unsigned short* __restrict__ xb,
                                                const unsigned short* __restrict__ wpbf,
                                                unsigned short* __restrict__ had) {
  __shared__ unsigned short sA[2][4096];
  const int tid = threadIdx.x;
  const int m0 = blockIdx.x * 128;
  const int yb = blockIdx.y;            // 0..1
  const int lane = tid & 63, wv = tid >> 6;
  const int wr = wv >> 1, wc = wv & 1;

  const floatx4 fz = {0.f, 0.f, 0.f, 0.f};
  floatx4 acc0[4][4], acc1[4][4];
#pragma unroll
  for (int i = 0; i < 4; ++i)
#pragma unroll
    for (int j = 0; j < 4; ++j) { acc0[i][j] = fz; acc1[i][j] = fz; }

  stage128x32(xb + (size_t)m0 * 384, 384, sA[0], tid);
  const unsigned short* bbase = wpbf + (size_t)(yb * 8 + wc * 4) * 6144 + lane * 8;

  int cur = 0;
#pragma unroll 1
  for (int s = 0; s < 12; ++s) {
    short8 b0[4], b1[4];
#pragma unroll
    for (int nf = 0; nf < 4; ++nf) {
      b0[nf] = *(const short8*)(bbase + (size_t)s * 512 + nf * 6144);
      b1[nf] = *(const short8*)(bbase + (size_t)s * 512 + nf * 6144 + 98304);
    }
    __syncthreads();
    if (s < 11) stage128x32(xb + (size_t)m0 * 384 + (s + 1) * 32, 384, sA[cur ^ 1], tid);
    short8 a[4];
#pragma unroll
    for (int mf = 0; mf < 4; ++mf)
      a[mf] = *(const short8*)&sA[cur][(wr * 64 + mf * 16 + (lane & 15)) * 32 + (lane >> 4) * 8];
#pragma unroll
    for (int mf = 0; mf < 4; ++mf)
#pragma unroll
      for (int nf = 0; nf < 4; ++nf) {
        acc0[mf][nf] = __builtin_amdgcn_mfma_f32_16x16x32_bf16(a[mf], b0[nf], acc0[mf][nf], 0, 0, 0);
        acc1[mf][nf] = __builtin_amdgcn_mfma_f32_16x16x32_bf16(a[mf], b1[nf], acc1[mf][nf], 0, 0, 0);
      }
    cur ^= 1;
  }

  const int colbase = yb * 128 + wc * 64;
#pragma unroll
  for (int mf = 0; mf < 4; ++mf)
#pragma unroll
    for (int nf = 0; nf < 4; ++nf) {
      const int col = colbase + nf * 16 + (lane & 15);
#pragma unroll
      for (int j = 0; j < 4; ++j) {
        const int row = m0 + wr * 64 + mf * 16 + (lane >> 4) * 4 + j;
        had[(size_t)row * 256 + col] = f2bf(acc0[mf][nf][j] * acc1[mf][nf][j] * SCALE);
      }
    }
}

// ---------------- Kernel A2: pre GEMM v (B frags from L2) ----------------
__global__ __launch_bounds__(256) void k_pre_v(const unsigned short* __restrict__ xb,
                                               const unsigned short* __restrict__ wpbf,
                                               unsigned short* __restrict__ vout) {
  __shared__ unsigned short sA[2][4096];
  const int tid = threadIdx.x;
  const int m0 = blockIdx.x * 128;
  const int yb = blockIdx.y;            // 0..2
  const int lane = tid & 63, wv = tid >> 6;
  const int wr = wv >> 1, wc = wv & 1;

  const floatx4 fz = {0.f, 0.f, 0.f, 0.f};
  floatx4 acc[4][4];
#pragma unroll
  for (int i = 0; i < 4; ++i)
#pragma unroll
    for (int j = 0; j < 4; ++j) acc[i][j] = fz;

  stage128x32(xb + (size_t)m0 * 384, 384, sA[0], tid);
  const unsigned short* bbase = wpbf + (size_t)(32 + yb * 8 + wc * 4) * 6144 + lane * 8;

  int cur = 0;
#pragma unroll 1
  for (int s = 0; s < 12; ++s) {
    short8 b[4];
#pragma unroll
    for (int nf = 0; nf < 4; ++nf)
      b[nf] = *(const short8*)(bbase + (size_t)s * 512 + nf * 6144);
    __syncthreads();
    if (s < 11) stage128x32(xb + (size_t)m0 * 384 + (s + 1) * 32, 384, sA[cur ^ 1], tid);
    short8 a[4];
#pragma unroll
    for (int mf = 0; mf < 4; ++mf)
      a[mf] = *(const short8*)&sA[cur][(wr * 64 + mf * 16 + (lane & 15)) * 32 + (lane >> 4) * 8];
#pragma unroll
    for (int mf = 0; mf < 4; ++mf)
#pragma unroll
      for (int nf = 0; nf < 4; ++nf)
        acc[mf][nf] = __builtin_amdgcn_mfma_f32_16x16x32_bf16(a[mf], b[nf], acc[mf][nf], 0, 0, 0);
    cur ^= 1;
  }

  const int colbase = yb * 128 + wc * 64;
#pragma unroll
  for (int mf = 0; mf < 4; ++mf)
#pragma unroll
    for (int nf = 0; nf < 4; ++nf) {
      const int col = colbase + nf * 16 + (lane & 15);
#pragma unroll
      for (int j = 0; j < 4; ++j) {
        const int row = m0 + wr * 64 + mf * 16 + (lane >> 4) * 4 + j;
        vout[(size_t)row * 384 + col] = f2bf(acc[mf][nf][j]);
      }
    }
}

// ---------------- Kernel B1: grouped 5x5 conv + GELU, MFMA version ----------------
__global__ __launch_bounds__(256) void k_conv_mfma(const unsigned short* __restrict__ had,
                                                   const unsigned short* __restrict__ w1mp,
                                                   const float* __restrict__ b1,
                                                   unsigned short* __restrict__ hm) {
  __shared__ unsigned short halo[8 * 288 * 8];  // 36,864 B
  const int tid = threadIdx.x;
  const int lane = tid & 63, wv = tid >> 6;
  const int bimg = blockIdx.x / 49;
  const int t49 = blockIdx.x % 49;
  const int y0 = (t49 / 7) * 8, x0 = (t49 % 7) * 8;
  const int half = blockIdx.y;
  const int c0 = half * 128;

  for (int ii = tid; ii < 2304; ii += 256) {
    const int g16 = ii & 15;       // pair*2 + h
    const int pyx = ii >> 4;       // 0..143
    const int py = pyx / 12, px = pyx % 12;
    const int gy = y0 + py - 2, gx = x0 + px - 2;
    uint4 val = make_uint4(0u, 0u, 0u, 0u);
    if (gy >= 0 && gy < 56 && gx >= 0 && gx < 56)
      val = *(const uint4*)(had + ((size_t)(bimg * 56 + gy) * 56 + gx) * 256 + c0 + g16 * 8);
    *(uint4*)&halo[(size_t)(((g16 >> 1) * 288 + (g16 & 1) * 144 + pyx)) * 8] = val;
  }
  __syncthreads();

  const int r = lane & 15;
  const int q = lane >> 4;
  const int h = q & 1, qh = q >> 1;

  const unsigned short* abase =
      &halo[(size_t)((wv * 2) * 288 + h * 144 + (r >> 3) * 12 + (r & 7)) * 8];
  const unsigned short* wq =
      w1mp + (size_t)((half * 8 + wv * 2) * 13) * 512 + lane * 8;

  const float bs0 = b1[(half * 8 + wv * 2) * 16 + r];
  const float bs1 = b1[(half * 8 + wv * 2 + 1) * 16 + r];

  floatx4 acc[2][4];
#pragma unroll
  for (int mf = 0; mf < 4; ++mf) {
    acc[0][mf] = (floatx4){bs0, bs0, bs0, bs0};
    acc[1][mf] = (floatx4){bs1, bs1, bs1, bs1};
  }

#pragma unroll
  for (int s = 0; s < 13; ++s) {
    const int t0 = 2 * s;
    const int t1 = (t0 + 1 > 24) ? 24 : t0 + 1;
    const int o0 = (t0 / 5) * 12 + (t0 % 5);
    const int o1 = (t1 / 5) * 12 + (t1 % 5);
    const unsigned short* ap = abase + (size_t)(qh ? o1 : o0) * 8;
    const short8 bf0 = *(const short8*)(wq + (size_t)s * 512);
    const short8 bf1 = *(const short8*)(wq + (size_t)(13 + s) * 512);
#pragma unroll
    for (int mf = 0; mf < 4; ++mf) {
      const short8 a0 = *(const short8*)(ap + mf * 192);
      acc[0][mf] = __builtin_amdgcn_mfma_f32_16x16x32_bf16(a0, bf0, acc[0][mf], 0, 0, 0);
    }
#pragma unroll
    for (int mf = 0; mf < 4; ++mf) {
      const short8 a1 = *(const short8*)(ap + 2304 + mf * 192);
      acc[1][mf] = __builtin_amdgcn_mfma_f32_16x16x32_bf16(a1, bf1, acc[1][mf], 0, 0, 0);
    }
  }

#pragma unroll
  for (int pp = 0; pp < 2; ++pp) {
    const int o = (half * 8 + wv * 2 + pp) * 16 + r;
#pragma unroll
    for (int mf = 0; mf < 4; ++mf)
#pragma unroll
      for (int j = 0; j < 4; ++j) {
        const int pix = mf * 16 + q * 4 + j;
        const int pyl = pix >> 3, pxl = pix & 7;
        const size_t gp = (size_t)(bimg * 56 + y0 + pyl) * 56 + (x0 + pxl);
        const float vv = acc[pp][mf][j];
        const float g = 0.5f * vv * (1.0f + erff(vv * 0.70710678118654752f));
        hm[gp * 256 + o] = f2bf(g);
      }
  }
}

// ---------------- Kernel B2: 1x1 GEMM + fused softmax, 64-px blocks ----------------
__global__ __launch_bounds__(256) void k_1x1s(const unsigned short* __restrict__ hm,
                                              const unsigned short* __restrict__ w2f,
                                              const float* __restrict__ b2,
                                              unsigned short* __restrict__ attn) {
  __shared__ unsigned short sA[2][2048];
  __shared__ unsigned short sw[4][16][312];
  const int tid = threadIdx.x;
  const int lane = tid & 63, wv = tid >> 6;
  const int m0 = blockIdx.x * 64;

  const floatx4 fz = {0.f, 0.f, 0.f, 0.f};
  floatx4 acc[19];
#pragma unroll
  for (int nf = 0; nf < 19; ++nf) acc[nf] = fz;

  stage64x32(hm + (size_t)m0 * 256, 256, sA[0], tid);
  const unsigned short* bbase = w2f + lane * 8;
  int cur = 0;
#pragma unroll 1
  for (int s = 0; s < 8; ++s) {
    short8 b[19];
#pragma unroll
    for (int nf = 0; nf < 19; ++nf)
      b[nf] = *(const short8*)(bbase + (size_t)(nf * 8 + s) * 512);
    __syncthreads();
    if (s < 7) stage64x32(hm + (size_t)m0 * 256 + (s + 1) * 32, 256, sA[cur ^ 1], tid);
    const short8 a = *(const short8*)&sA[cur][(wv * 16 + (lane & 15)) * 32 + (lane >> 4) * 8];
#pragma unroll
    for (int nf = 0; nf < 19; ++nf)
      acc[nf] = __builtin_amdgcn_mfma_f32_16x16x32_bf16(a, b[nf], acc[nf], 0, 0, 0);
    cur ^= 1;
  }
  __syncthreads();

#pragma unroll
  for (int nf = 0; nf < 19; ++nf) {
    const int col = nf * 16 + (lane & 15);
    const float bias = (col < 300) ? b2[col] : 0.f;
#pragma unroll
    for (int j = 0; j < 4; ++j) {
      const int row = (lane >> 4) * 4 + j;
      sw[wv][row][col] = f2bf(acc[nf][j] + bias);
    }
  }
  __syncthreads();

#pragma unroll
  for (int t = 0; t < 3; ++t) {
    const int tt = t * 64 + lane;
    const int px = tt & 15, g = tt >> 4;
    unsigned short* srow = &sw[wv][px][g * 25];
    float a2[25];
#pragma unroll
    for (int kk = 0; kk < 25; ++kk) a2[kk] = bf2f(srow[kk]);
    float m = a2[0];
#pragma unroll
    for (int kk = 1; kk < 25; ++kk) m = fmaxf(m, a2[kk]);
    float s = 0.f;
#pragma unroll
    for (int kk = 0; kk < 25; ++kk) { a2[kk] = __expf(a2[kk] - m); s += a2[kk]; }
    const float rr = 1.0f / s;
#pragma unroll
    for (int kk = 0; kk < 25; ++kk) srow[kk] = f2bf(a2[kk] * rr);
  }
  __syncthreads();

  const unsigned short* swl = &sw[0][0][0];
  for (int i = tid; i < 4800; i += 256) {
    const int r = i / 75, c = i % 75;
    const uint2 val = *(const uint2*)(swl + (size_t)r * 312 + c * 4);
    *(uint2*)(attn + (size_t)(m0 + r) * 300 + c * 4) = val;
  }
}

// ---------------- Kernel C: ELSA aggregation v8 (best measured: 70 us) ----------------
// Round-12 structure (no register pipeline) + LDS-staged attn.
__global__ __launch_bounds__(512) void k_elsa(const unsigned short* __restrict__ v,
                                              const unsigned short* __restrict__ attn,
                                              const float* __restrict__ ggp,
                                              unsigned short* __restrict__ outp) {
  __shared__ float sGG[25 * 16 * 16];    // 25,600 B
  __shared__ unsigned short sAt[64][104];  // 13,312 B
  const int tid = threadIdx.x;
  const int chunk = blockIdx.y;
  const int pb = blockIdx.x * 64;

  {
    const float4* src = (const float4*)(ggp + (size_t)chunk * 6400);
    float4* dst = (float4*)sGG;
    for (int j = tid; j < 1600; j += 512) dst[j] = src[j];
  }
  // stage attn: 64 rows x 100 u16 (this chunk's 4 heads), dense 8B loads
  for (int j = tid; j < 1600; j += 512) {
    const int r = j / 25, c = j % 25;    // c in uint2 units
    const uint2 val = *(const uint2*)(attn + (size_t)(pb + r) * 300 + chunk * 100 + c * 4);
    *(uint2*)&sAt[r][c * 4] = val;
  }
  __syncthreads();

  const int ol = tid & 15;
  const int og = chunk * 16 + ol;
  const int pxi = tid >> 4;           // 0..31
  const int gl = ol >> 2;             // head within chunk
  const int swz = (ol >> 1) & 3;
  const int p0 = blockIdx.x * 64 + pxi * 2;
  const int xp = p0 % 56;
  const int yp = (p0 / 56) % 56;
  const int pxl = pxi * 2;

  const unsigned short* __restrict__ vb = v + ((size_t)p0 - 114) * 384 + og * 8;

  float acc0[8], acc1[8];
#pragma unroll
  for (int i = 0; i < 8; ++i) { acc0[i] = 0.f; acc1[i] = 0.f; }

  const u16x8 hz = {0, 0, 0, 0, 0, 0, 0, 0};

#pragma unroll 1
  for (int dy = 0; dy < 5; ++dy) {
    const bool rowok = (unsigned)(yp + dy - 2) < 56u;
    u16x8 hv[6];
#pragma unroll
    for (int j = 0; j < 6; ++j) {
      const bool ok = rowok && ((unsigned)(xp - 2 + j) < 56u);
      hv[j] = ok ? *(const u16x8*)(vb + ((size_t)dy * 56 + j) * 384) : hz;
    }
#pragma unroll
    for (int t = 0; t < 5; ++t) {
      const int kk = dy * 5 + t;
      const float* gg = &sGG[(kk * 16 + ol) << 4];
      const float4 gm0 = *(const float4*)(gg + ((0 ^ swz) << 2));
      const float4 gm1 = *(const float4*)(gg + ((1 ^ swz) << 2));
      const float4 ga0 = *(const float4*)(gg + ((2 ^ swz) << 2));
      const float4 ga1 = *(const float4*)(gg + ((3 ^ swz) << 2));
      const float a0 = bf2f(sAt[pxl][gl * 25 + kk]);
      const float a1 = bf2f(sAt[pxl + 1][gl * 25 + kk]);
      acc0[0] = fmaf(bf2f(hv[t][0]), fmaf(gm0.x, a0, ga0.x), acc0[0]);
      acc0[1] = fmaf(bf2f(hv[t][1]), fmaf(gm0.y, a0, ga0.y), acc0[1]);
      acc0[2] = fmaf(bf2f(hv[t][2]), fmaf(gm0.z, a0, ga0.z), acc0[2]);
      acc0[3] = fmaf(bf2f(hv[t][3]), fmaf(gm0.w, a0, ga0.w), acc0[3]);
      acc0[4] = fmaf(bf2f(hv[t][4]), fmaf(gm1.x, a0, ga1.x), acc0[4]);
      acc0[5] = fmaf(bf2f(hv[t][5]), fmaf(gm1.y, a0, ga1.y), acc0[5]);
      acc0[6] = fmaf(bf2f(hv[t][6]), fmaf(gm1.z, a0, ga1.z), acc0[6]);
      acc0[7] = fmaf(bf2f(hv[t][7]), fmaf(gm1.w, a0, ga1.w), acc0[7]);
      acc1[0] = fmaf(bf2f(hv[t + 1][0]), fmaf(gm0.x, a1, ga0.x), acc1[0]);
      acc1[1] = fmaf(bf2f(hv[t + 1][1]), fmaf(gm0.y, a1, ga0.y), acc1[1]);
      acc1[2] = fmaf(bf2f(hv[t + 1][2]), fmaf(gm0.z, a1, ga0.z), acc1[2]);
      acc1[3] = fmaf(bf2f(hv[t + 1][3]), fmaf(gm0.w, a1, ga0.w), acc1[3]);
      acc1[4] = fmaf(bf2f(hv[t + 1][4]), fmaf(gm1.x, a1, ga1.x), acc1[4]);
      acc1[5] = fmaf(bf2f(hv[t + 1][5]), fmaf(gm1.y, a1, ga1.y), acc1[5]);
      acc1[6] = fmaf(bf2f(hv[t + 1][6]), fmaf(gm1.z, a1, ga1.z), acc1[6]);
      acc1[7] = fmaf(bf2f(hv[t + 1][7]), fmaf(gm1.w, a1, ga1.w), acc1[7]);
    }
  }

  u16x8 ov0, ov1;
#pragma unroll
  for (int i = 0; i < 8; ++i) { ov0[i] = f2bf(acc0[i]); ov1[i] = f2bf(acc1[i]); }
  *(u16x8*)(outp + (size_t)p0 * 384 + og * 8) = ov0;
  *(u16x8*)(outp + (size_t)(p0 + 1) * 384 + og * 8) = ov1;
}

// ---------------- Kernel D: post GEMM (hi/lo B frags from L2) ----------------
__global__ __launch_bounds__(256) void k_post_mfma(const unsigned short* __restrict__ outp,
                                                   const unsigned short* __restrict__ wpostf,
                                                   const float* __restrict__ b_post,
                                                   float* __restrict__ out) {
  __shared__ unsigned short sA[2][4096];
  const int tid = threadIdx.x;
  const int m0 = blockIdx.x * 128;
  const int yb = blockIdx.y;            // 0..2
  const int lane = tid & 63, wv = tid >> 6;
  const int wr = wv >> 1, wc = wv & 1;

  const floatx4 fz = {0.f, 0.f, 0.f, 0.f};
  floatx4 acc[4][4];
#pragma unroll
  for (int i = 0; i < 4; ++i)
#pragma unroll
    for (int j = 0; j < 4; ++j) acc[i][j] = fz;

  stage128x32(outp + (size_t)m0 * 384, 384, sA[0], tid);
  const unsigned short* bbase = wpostf + (size_t)(yb * 8 + wc * 4) * 6144 + lane * 8;

  int cur = 0;
#pragma unroll 1
  for (int s = 0; s < 12; ++s) {
    short8 bh[4], bl[4];
#pragma unroll
    for (int nf = 0; nf < 4; ++nf) {
      bh[nf] = *(const short8*)(bbase + (size_t)s * 512 + nf * 6144);
      bl[nf] = *(const short8*)(bbase + (size_t)s * 512 + nf * 6144 + 147456);
    }
    __syncthreads();
    if (s < 11) stage128x32(outp + (size_t)m0 * 384 + (s + 1) * 32, 384, sA[cur ^ 1], tid);
    short8 a[4];
#pragma unroll
    for (int mf = 0; mf < 4; ++mf)
      a[mf] = *(const short8*)&sA[cur][(wr * 64 + mf * 16 + (lane & 15)) * 32 + (lane >> 4) * 8];
#pragma unroll
    for (int mf = 0; mf < 4; ++mf)
#pragma unroll
      for (int nf = 0; nf < 4; ++nf) {
        acc[mf][nf] = __builtin_amdgcn_mfma_f32_16x16x32_bf16(a[mf], bh[nf], acc[mf][nf], 0, 0, 0);
        acc[mf][nf] = __builtin_amdgcn_mfma_f32_16x16x32_bf16(a[mf], bl[nf], acc[mf][nf], 0, 0, 0);
      }
    cur ^= 1;
  }

#pragma unroll
  for (int mf = 0; mf < 4; ++mf)
#pragma unroll
    for (int nf = 0; nf < 4; ++nf) {
      const int col = yb * 128 + wc * 64 + nf * 16 + (lane & 15);
      const float bias = b_post[col];
#pragma unroll
      for (int j = 0; j < 4; ++j) {
        const int row = m0 + wr * 64 + mf * 16 + (lane >> 4) * 4 + j;
        out[(size_t)row * 384 + col] = acc[mf][nf][j] + bias;
      }
    }
}

extern "C" void kernel_launch(void* const* d_in, const int* in_sizes, int n_in,
                              void* d_out, int out_size, void* d_ws, size_t ws_size,
                              hipStream_t stream) {
  const float* x      = (const float*)d_in[0];
  const float* w_pre  = (const float*)d_in[1];
  const float* w1     = (const float*)d_in[2];
  const float* b1     = (const float*)d_in[3];
  const float* w2     = (const float*)d_in[4];
  const float* b2     = (const float*)d_in[5];
  const float* gh     = (const float*)d_in[6];
  const float* w_post = (const float*)d_in[7];
  const float* b_post = (const float*)d_in[8];
  float* out = (float*)d_out;

  char* ws = (char*)d_ws;
  unsigned short* xb     = (unsigned short*)ws;
  unsigned short* hm     = (unsigned short*)ws;
  unsigned short* w1mp   = (unsigned short*)(ws + 25690112);
  unsigned short* w2f    = (unsigned short*)(ws + 25903104);    // 155,648 B
  unsigned short* outp   = (unsigned short*)ws;
  unsigned short* had    = (unsigned short*)(ws + 38535168);
  float*          ggp    = (float*)(ws + 38535168);             // reuses dead `had`
  unsigned short* v      = (unsigned short*)(ws + 64225280);
  unsigned short* attn   = (unsigned short*)(ws + 102760448);
  unsigned short* wpbf   = (unsigned short*)(ws + 132866048);   // 688,128 B (56 groups)
  unsigned short* wpostf = (unsigned short*)(ws + 133554176);   // 589,824 B (hi+lo)

  k_cvt<<<dim3(2048), dim3(256), 0, stream>>>(x, xb, 19267584 / 8);
  k_wfrag<<<dim3(1344), dim3(256), 0, stream>>>(w_pre, wpbf, 344064);
  k_wpostf<<<dim3(1152), dim3(256), 0, stream>>>(w_post, wpostf);

  k_pre_qk<<<dim3(392, 2), dim3(256), 0, stream>>>(xb, wpbf, had);
  k_pre_v<<<dim3(392, 3), dim3(256), 0, stream>>>(xb, wpbf, v);

  // xb dead now; pack small weights into R0 slack
  k_w1mpack<<<dim3(416), dim3(256), 0, stream>>>(w1, w1mp);
  k_w2frag<<<dim3(304), dim3(256), 0, stream>>>(w2, w2f);

  k_conv_mfma<<<dim3(784, 2), dim3(256), 0, stream>>>(had, w1mp, b1, hm);
  // had dead now; ggp reuses its storage (outside R0, so k_elsa's outp writes
  // cannot clobber it)
  k_ggpack<<<dim3(75), dim3(256), 0, stream>>>(gh, ggp);
  k_1x1s<<<dim3(784), dim3(256), 0, stream>>>(hm, w2f, b2, attn);
  k_elsa<<<dim3(784, 3), dim3(512), 0, stream>>>(v, attn, ggp, outp);
  k_post_mfma<<<dim3(392, 3), dim3(256), 0, stream>>>(outp, wpostf, b_post, out);
}

// Round 18
// 281.549 us; speedup vs baseline: 1.0506x; 1.0034x over previous
//
#include <hip/hip_runtime.h>
#include <hip/hip_bf16.h>

#define NPX 50176
#define SCALE 0.17677669529663687f

typedef __attribute__((ext_vector_type(8))) short short8;
typedef __attribute__((ext_vector_type(4))) float floatx4;
using u16x8 = __attribute__((ext_vector_type(8))) unsigned short;

static __device__ __forceinline__ float bf2f(unsigned short u) {
  union { unsigned int i; float f; } c; c.i = ((unsigned int)u) << 16; return c.f;
}
static __device__ __forceinline__ unsigned short f2bf(float f) {
  union { float f; unsigned int i; } c; c.f = f;
  unsigned int u = c.i;
  u += 0x7fffu + ((u >> 16) & 1u);
  return (unsigned short)(u >> 16);
}

static __device__ __forceinline__ void gl_lds16(const unsigned short* g, unsigned short* l) {
  __builtin_amdgcn_global_load_lds(
      (const __attribute__((address_space(1))) void*)g,
      (__attribute__((address_space(3))) void*)l, 16, 0, 0);
}

// stage a 128x32 bf16 tile (row stride ldK elems) into linear LDS [128][32] (4096 u16)
static __device__ __forceinline__ void stage128x32(const unsigned short* g, int ldK,
                                                   unsigned short* lds, int tid) {
  const int wv = tid >> 6, lane = tid & 63;
#pragma unroll
  for (int i = 0; i < 2; ++i) {
    const int ci = i * 4 + wv;
    const int row = ci * 16 + (lane >> 2);
    const int col = (lane & 3) * 8;
    gl_lds16(g + (size_t)row * ldK + col, lds + ci * 512);
  }
}

// stage a 64x32 bf16 tile into linear LDS [64][32] (2048 u16); 1 granule/thread
static __device__ __forceinline__ void stage64x32(const unsigned short* g, int ldK,
                                                  unsigned short* lds, int tid) {
  const int row = tid >> 2;
  const int col = (tid & 3) * 8;
  gl_lds16(g + (size_t)row * ldK + col, lds + tid * 8);
}

// ---------------- converters / packers ----------------
__global__ __launch_bounds__(256) void k_cvt(const float* __restrict__ src,
                                             unsigned short* __restrict__ dst, int n8) {
  int i = blockIdx.x * 256 + threadIdx.x;
  const int stride = gridDim.x * 256;
  for (; i < n8; i += stride) {
    float4 f0 = *(const float4*)(src + (size_t)i * 8);
    float4 f1 = *(const float4*)(src + (size_t)i * 8 + 4);
    u16x8 o;
    o[0] = f2bf(f0.x); o[1] = f2bf(f0.y); o[2] = f2bf(f0.z); o[3] = f2bf(f0.w);
    o[4] = f2bf(f1.x); o[5] = f2bf(f1.y); o[6] = f2bf(f1.z); o[7] = f2bf(f1.w);
    *(u16x8*)(dst + (size_t)i * 8) = o;
  }
}

// fragment-pack a [ncols x 384] f32 row-major matrix into [g][s][lane][8] bf16
__global__ __launch_bounds__(256) void k_wfrag(const float* __restrict__ w,
                                               unsigned short* __restrict__ dst, int ntot) {
  int idx = blockIdx.x * 256 + threadIdx.x;
  if (idx < ntot) {
    int e = idx & 7;
    int lane = (idx >> 3) & 63;
    int s = (idx >> 9) % 12;
    int g = (idx >> 9) / 12;
    int col = g * 16 + (lane & 15);
    int k = s * 32 + (lane >> 4) * 8 + e;
    dst[idx] = f2bf(w[(size_t)col * 384 + k]);
  }
}

// fragment-pack w_post into hi/lo split: dst[h][g 24][s 12][lane][8]
__global__ __launch_bounds__(256) void k_wpostf(const float* __restrict__ w,
                                                unsigned short* __restrict__ dst) {
  int idx = blockIdx.x * 256 + threadIdx.x;  // 2*24*12*512 = 294912
  if (idx < 294912) {
    int e = idx & 7;
    int lane = (idx >> 3) & 63;
    int s = (idx >> 9) % 12;
    int gh = (idx >> 9) / 12;   // 0..47
    int g = gh % 24, h = gh / 24;
    int col = g * 16 + (lane & 15);
    int k = s * 32 + (lane >> 4) * 8 + e;
    float f = w[(size_t)col * 384 + k];
    unsigned short hi = f2bf(f);
    dst[idx] = (h == 0) ? hi : f2bf(f - bf2f(hi));
  }
}

// w1mp[pairg 16][s 13][lane 64][i 8] bf16, exact 16x16x32 MFMA B-fragment order.
__global__ __launch_bounds__(256) void k_w1mpack(const float* __restrict__ w1,
                                                 unsigned short* __restrict__ w1mp) {
  int idx = blockIdx.x * 256 + threadIdx.x;  // 16*13*64*8 = 106496
  if (idx < 106496) {
    int i = idx & 7;
    int lane = (idx >> 3) & 63;
    int ps = idx >> 9;          // pairg*13 + s
    int s = ps % 13;
    int pairg = ps / 13;
    int n = lane & 15, qq = lane >> 4;
    int k = s * 32 + qq * 8 + i;
    int t = k >> 4, ich = k & 15;
    int o = pairg * 16 + n;
    float v = 0.f;
    if (t < 25 && (ich >> 3) == (n >> 3))
      v = w1[o * 200 + (ich & 7) * 25 + t];
    w1mp[idx] = f2bf(v);
  }
}

// w2f[g 19][s 8][lane][8] bf16, MFMA B-fragment order (cols 300..303 zero)
__global__ __launch_bounds__(256) void k_w2frag(const float* __restrict__ w2,
                                                unsigned short* __restrict__ w2f) {
  int idx = blockIdx.x * 256 + threadIdx.x;  // 19*8*512 = 77824
  if (idx < 77824) {
    int e = idx & 7;
    int lane = (idx >> 3) & 63;
    int s = (idx >> 9) & 7;
    int g = idx >> 12;
    int col = g * 16 + (lane & 15);
    int k = s * 32 + (lane >> 4) * 8 + e;
    w2f[idx] = (col < 300) ? f2bf(w2[(size_t)col * 256 + k]) : (unsigned short)0;
  }
}

// ggp[chunk 3][kk 25][ol 16][q 4][i 4] f32 — the EXACT swizzled LDS image each
// k_elsa chunk needs (phys granule q holds logical L = q ^ ((ol>>1)&3)).
__global__ __launch_bounds__(256) void k_ggpack(const float* __restrict__ gh,
                                                float* __restrict__ ggp) {
  int idx = blockIdx.x * 256 + threadIdx.x;  // 3*25*16*16 = 19200
  if (idx < 19200) {
    int i = idx & 3;
    int q = (idx >> 2) & 3;
    int ol = (idx >> 4) & 15;
    int kk = (idx >> 8) % 25;
    int chunk = idx / 6400;
    int swz = (ol >> 1) & 3;
    int L = q ^ swz;
    int og = chunk * 16 + ol;
    ggp[idx] = gh[(L >> 1) * 9600 + (og * 8 + (L & 1) * 4 + i) * 25 + kk];
  }
}

// ---------------- Kernel A1: pre GEMM q&k + hadamard (B frags from L2) ----------------
__global__ __launch_bounds__(256) void k_pre_qk(const unsigned short* __restrict__ xb,
                                                const unsigned short* __restrict__ wpbf,
                                                unsigned short* __restrict__ had) {
  __shared__ unsigned short sA[2][4096];
  const int tid = threadIdx.x;
  const int m0 = blockIdx.x * 128;
  const int yb = blockIdx.y;            // 0..1
  const int lane = tid & 63, wv = tid >> 6;
  const int wr = wv >> 1, wc = wv & 1;

  const floatx4 fz = {0.f, 0.f, 0.f, 0.f};
  floatx4 acc0[4][4], acc1[4][4];
#pragma unroll
  for (int i = 0; i < 4; ++i)
#pragma unroll
    for (int j = 0; j < 4; ++j) { acc0[i][j] = fz; acc1[i][j] = fz; }

  stage128x32(xb + (size_t)m0 * 384, 384, sA[0], tid);
  const unsigned short* bbase = wpbf + (size_t)(yb * 8 + wc * 4) * 6144 + lane * 8;

  int cur = 0;
#pragma unroll 1
  for (int s = 0; s < 12; ++s) {
    short8 b0[4], b1[4];
#pragma unroll
    for (int nf = 0; nf < 4; ++nf) {
      b0[nf] = *(const short8*)(bbase + (size_t)s * 512 + nf * 6144);
      b1[nf] = *(const short8*)(bbase + (size_t)s * 512 + nf * 6144 + 98304);
    }
    __syncthreads();
    if (s < 11) stage128x32(xb + (size_t)m0 * 384 + (s + 1) * 32, 384, sA[cur ^ 1], tid);
    short8 a[4];
#pragma unroll
    for (int mf = 0; mf < 4; ++mf)
      a[mf] = *(const short8*)&sA[cur][(wr * 64 + mf * 16 + (lane & 15)) * 32 + (lane >> 4) * 8];
#pragma unroll
    for (int mf = 0; mf < 4; ++mf)
#pragma unroll
      for (int nf = 0; nf < 4; ++nf) {
        acc0[mf][nf] = __builtin_amdgcn_mfma_f32_16x16x32_bf16(a[mf], b0[nf], acc0[mf][nf], 0, 0, 0);
        acc1[mf][nf] = __builtin_amdgcn_mfma_f32_16x16x32_bf16(a[mf], b1[nf], acc1[mf][nf], 0, 0, 0);
      }
    cur ^= 1;
  }

  const int colbase = yb * 128 + wc * 64;
#pragma unroll
  for (int mf = 0; mf < 4; ++mf)
#pragma unroll
    for (int nf = 0; nf < 4; ++nf) {
      const int col = colbase + nf * 16 + (lane & 15);
#pragma unroll
      for (int j = 0; j < 4; ++j) {
        const int row = m0 + wr * 64 + mf * 16 + (lane >> 4) * 4 + j;
        had[(size_t)row * 256 + col] = f2bf(acc0[mf][nf][j] * acc1[mf][nf][j] * SCALE);
      }
    }
}

// ---------------- Kernel A2: pre GEMM v (B frags from L2) ----------------
__global__ __launch_bounds__(256) void k_pre_v(const unsigned short* __restrict__ xb,
                                               const unsigned short* __restrict__ wpbf,
                                               unsigned short* __restrict__ vout) {
  __shared__ unsigned short sA[2][4096];
  const int tid = threadIdx.x;
  const int m0 = blockIdx.x * 128;
  const int yb = blockIdx.y;            // 0..2
  const int lane = tid & 63, wv = tid >> 6;
  const int wr = wv >> 1, wc = wv & 1;

  const floatx4 fz = {0.f, 0.f, 0.f, 0.f};
  floatx4 acc[4][4];
#pragma unroll
  for (int i = 0; i < 4; ++i)
#pragma unroll
    for (int j = 0; j < 4; ++j) acc[i][j] = fz;

  stage128x32(xb + (size_t)m0 * 384, 384, sA[0], tid);
  const unsigned short* bbase = wpbf + (size_t)(32 + yb * 8 + wc * 4) * 6144 + lane * 8;

  int cur = 0;
#pragma unroll 1
  for (int s = 0; s < 12; ++s) {
    short8 b[4];
#pragma unroll
    for (int nf = 0; nf < 4; ++nf)
      b[nf] = *(const short8*)(bbase + (size_t)s * 512 + nf * 6144);
    __syncthreads();
    if (s < 11) stage128x32(xb + (size_t)m0 * 384 + (s + 1) * 32, 384, sA[cur ^ 1], tid);
    short8 a[4];
#pragma unroll
    for (int mf = 0; mf < 4; ++mf)
      a[mf] = *(const short8*)&sA[cur][(wr * 64 + mf * 16 + (lane & 15)) * 32 + (lane >> 4) * 8];
#pragma unroll
    for (int mf = 0; mf < 4; ++mf)
#pragma unroll
      for (int nf = 0; nf < 4; ++nf)
        acc[mf][nf] = __builtin_amdgcn_mfma_f32_16x16x32_bf16(a[mf], b[nf], acc[mf][nf], 0, 0, 0);
    cur ^= 1;
  }

  const int colbase = yb * 128 + wc * 64;
#pragma unroll
  for (int mf = 0; mf < 4; ++mf)
#pragma unroll
    for (int nf = 0; nf < 4; ++nf) {
      const int col = colbase + nf * 16 + (lane & 15);
#pragma unroll
      for (int j = 0; j < 4; ++j) {
        const int row = m0 + wr * 64 + mf * 16 + (lane >> 4) * 4 + j;
        vout[(size_t)row * 384 + col] = f2bf(acc[mf][nf][j]);
      }
    }
}

// ---------------- Kernel B1: grouped 5x5 conv + GELU, MFMA; XCD-swizzled ----------------
__global__ __launch_bounds__(256) void k_conv_mfma(const unsigned short* __restrict__ had,
                                                   const unsigned short* __restrict__ w1mp,
                                                   const float* __restrict__ b1,
                                                   unsigned short* __restrict__ hm) {
  __shared__ unsigned short halo[8 * 288 * 8];  // 36,864 B
  const int tid = threadIdx.x;
  const int lane = tid & 63, wv = tid >> 6;
  // XCD-aware bijective swizzle (784 % 8 == 0): each XCD gets 98 contiguous
  // tiles -> halo rows reused in its private L2.
  const int bxs = (blockIdx.x & 7) * 98 + (blockIdx.x >> 3);
  const int bimg = bxs / 49;
  const int t49 = bxs % 49;
  const int y0 = (t49 / 7) * 8, x0 = (t49 % 7) * 8;
  const int half = blockIdx.y;
  const int c0 = half * 128;

  for (int ii = tid; ii < 2304; ii += 256) {
    const int g16 = ii & 15;       // pair*2 + h
    const int pyx = ii >> 4;       // 0..143
    const int py = pyx / 12, px = pyx % 12;
    const int gy = y0 + py - 2, gx = x0 + px - 2;
    uint4 val = make_uint4(0u, 0u, 0u, 0u);
    if (gy >= 0 && gy < 56 && gx >= 0 && gx < 56)
      val = *(const uint4*)(had + ((size_t)(bimg * 56 + gy) * 56 + gx) * 256 + c0 + g16 * 8);
    *(uint4*)&halo[(size_t)(((g16 >> 1) * 288 + (g16 & 1) * 144 + pyx)) * 8] = val;
  }
  __syncthreads();

  const int r = lane & 15;
  const int q = lane >> 4;
  const int h = q & 1, qh = q >> 1;

  const unsigned short* abase =
      &halo[(size_t)((wv * 2) * 288 + h * 144 + (r >> 3) * 12 + (r & 7)) * 8];
  const unsigned short* wq =
      w1mp + (size_t)((half * 8 + wv * 2) * 13) * 512 + lane * 8;

  const float bs0 = b1[(half * 8 + wv * 2) * 16 + r];
  const float bs1 = b1[(half * 8 + wv * 2 + 1) * 16 + r];

  floatx4 acc[2][4];
#pragma unroll
  for (int mf = 0; mf < 4; ++mf) {
    acc[0][mf] = (floatx4){bs0, bs0, bs0, bs0};
    acc[1][mf] = (floatx4){bs1, bs1, bs1, bs1};
  }

#pragma unroll
  for (int s = 0; s < 13; ++s) {
    const int t0 = 2 * s;
    const int t1 = (t0 + 1 > 24) ? 24 : t0 + 1;
    const int o0 = (t0 / 5) * 12 + (t0 % 5);
    const int o1 = (t1 / 5) * 12 + (t1 % 5);
    const unsigned short* ap = abase + (size_t)(qh ? o1 : o0) * 8;
    const short8 bf0 = *(const short8*)(wq + (size_t)s * 512);
    const short8 bf1 = *(const short8*)(wq + (size_t)(13 + s) * 512);
#pragma unroll
    for (int mf = 0; mf < 4; ++mf) {
      const short8 a0 = *(const short8*)(ap + mf * 192);
      acc[0][mf] = __builtin_amdgcn_mfma_f32_16x16x32_bf16(a0, bf0, acc[0][mf], 0, 0, 0);
    }
#pragma unroll
    for (int mf = 0; mf < 4; ++mf) {
      const short8 a1 = *(const short8*)(ap + 2304 + mf * 192);
      acc[1][mf] = __builtin_amdgcn_mfma_f32_16x16x32_bf16(a1, bf1, acc[1][mf], 0, 0, 0);
    }
  }

#pragma unroll
  for (int pp = 0; pp < 2; ++pp) {
    const int o = (half * 8 + wv * 2 + pp) * 16 + r;
#pragma unroll
    for (int mf = 0; mf < 4; ++mf)
#pragma unroll
      for (int j = 0; j < 4; ++j) {
        const int pix = mf * 16 + q * 4 + j;
        const int pyl = pix >> 3, pxl = pix & 7;
        const size_t gp = (size_t)(bimg * 56 + y0 + pyl) * 56 + (x0 + pxl);
        const float vv = acc[pp][mf][j];
        const float g = 0.5f * vv * (1.0f + erff(vv * 0.70710678118654752f));
        hm[gp * 256 + o] = f2bf(g);
      }
  }
}

// ---------------- Kernel B2: 1x1 GEMM + fused softmax, 64-px blocks ----------------
__global__ __launch_bounds__(256) void k_1x1s(const unsigned short* __restrict__ hm,
                                              const unsigned short* __restrict__ w2f,
                                              const float* __restrict__ b2,
                                              unsigned short* __restrict__ attn) {
  __shared__ unsigned short sA[2][2048];
  __shared__ unsigned short sw[4][16][312];
  const int tid = threadIdx.x;
  const int lane = tid & 63, wv = tid >> 6;
  const int m0 = blockIdx.x * 64;

  const floatx4 fz = {0.f, 0.f, 0.f, 0.f};
  floatx4 acc[19];
#pragma unroll
  for (int nf = 0; nf < 19; ++nf) acc[nf] = fz;

  stage64x32(hm + (size_t)m0 * 256, 256, sA[0], tid);
  const unsigned short* bbase = w2f + lane * 8;
  int cur = 0;
#pragma unroll 1
  for (int s = 0; s < 8; ++s) {
    short8 b[19];
#pragma unroll
    for (int nf = 0; nf < 19; ++nf)
      b[nf] = *(const short8*)(bbase + (size_t)(nf * 8 + s) * 512);
    __syncthreads();
    if (s < 7) stage64x32(hm + (size_t)m0 * 256 + (s + 1) * 32, 256, sA[cur ^ 1], tid);
    const short8 a = *(const short8*)&sA[cur][(wv * 16 + (lane & 15)) * 32 + (lane >> 4) * 8];
#pragma unroll
    for (int nf = 0; nf < 19; ++nf)
      acc[nf] = __builtin_amdgcn_mfma_f32_16x16x32_bf16(a, b[nf], acc[nf], 0, 0, 0);
    cur ^= 1;
  }
  __syncthreads();

#pragma unroll
  for (int nf = 0; nf < 19; ++nf) {
    const int col = nf * 16 + (lane & 15);
    const float bias = (col < 300) ? b2[col] : 0.f;
#pragma unroll
    for (int j = 0; j < 4; ++j) {
      const int row = (lane >> 4) * 4 + j;
      sw[wv][row][col] = f2bf(acc[nf][j] + bias);
    }
  }
  __syncthreads();

#pragma unroll
  for (int t = 0; t < 3; ++t) {
    const int tt = t * 64 + lane;
    const int px = tt & 15, g = tt >> 4;
    unsigned short* srow = &sw[wv][px][g * 25];
    float a2[25];
#pragma unroll
    for (int kk = 0; kk < 25; ++kk) a2[kk] = bf2f(srow[kk]);
    float m = a2[0];
#pragma unroll
    for (int kk = 1; kk < 25; ++kk) m = fmaxf(m, a2[kk]);
    float s = 0.f;
#pragma unroll
    for (int kk = 0; kk < 25; ++kk) { a2[kk] = __expf(a2[kk] - m); s += a2[kk]; }
    const float rr = 1.0f / s;
#pragma unroll
    for (int kk = 0; kk < 25; ++kk) srow[kk] = f2bf(a2[kk] * rr);
  }
  __syncthreads();

  const unsigned short* swl = &sw[0][0][0];
  for (int i = tid; i < 4800; i += 256) {
    const int r = i / 75, c = i % 75;
    const uint2 val = *(const uint2*)(swl + (size_t)r * 312 + c * 4);
    *(uint2*)(attn + (size_t)(m0 + r) * 300 + c * 4) = val;
  }
}

// ---------------- Kernel C: ELSA aggregation v8 + XCD swizzle ----------------
// v8 structure (best measured), plus XCD-aware bijective blockIdx.x swizzle
// (784 % 8 == 0): each XCD owns 98 contiguous 64-px blocks (~112 image rows),
// so the dy-halo v rows hit its private L2 instead of re-fetching from HBM.
__global__ __launch_bounds__(512) void k_elsa(const unsigned short* __restrict__ v,
                                              const unsigned short* __restrict__ attn,
                                              const float* __restrict__ ggp,
                                              unsigned short* __restrict__ outp) {
  __shared__ float sGG[25 * 16 * 16];    // 25,600 B
  __shared__ unsigned short sAt[64][104];  // 13,312 B
  const int tid = threadIdx.x;
  const int chunk = blockIdx.y;
  const int bxs = (blockIdx.x & 7) * 98 + (blockIdx.x >> 3);
  const int pb = bxs * 64;

  {
    const float4* src = (const float4*)(ggp + (size_t)chunk * 6400);
    float4* dst = (float4*)sGG;
    for (int j = tid; j < 1600; j += 512) dst[j] = src[j];
  }
  // stage attn: 64 rows x 100 u16 (this chunk's 4 heads), dense 8B loads
  for (int j = tid; j < 1600; j += 512) {
    const int r = j / 25, c = j % 25;    // c in uint2 units
    const uint2 val = *(const uint2*)(attn + (size_t)(pb + r) * 300 + chunk * 100 + c * 4);
    *(uint2*)&sAt[r][c * 4] = val;
  }
  __syncthreads();

  const int ol = tid & 15;
  const int og = chunk * 16 + ol;
  const int pxi = tid >> 4;           // 0..31
  const int gl = ol >> 2;             // head within chunk
  const int swz = (ol >> 1) & 3;
  const int p0 = pb + pxi * 2;
  const int xp = p0 % 56;
  const int yp = (p0 / 56) % 56;
  const int pxl = pxi * 2;

  const unsigned short* __restrict__ vb = v + ((size_t)p0 - 114) * 384 + og * 8;

  float acc0[8], acc1[8];
#pragma unroll
  for (int i = 0; i < 8; ++i) { acc0[i] = 0.f; acc1[i] = 0.f; }

  const u16x8 hz = {0, 0, 0, 0, 0, 0, 0, 0};

#pragma unroll 1
  for (int dy = 0; dy < 5; ++dy) {
    const bool rowok = (unsigned)(yp + dy - 2) < 56u;
    u16x8 hv[6];
#pragma unroll
    for (int j = 0; j < 6; ++j) {
      const bool ok = rowok && ((unsigned)(xp - 2 + j) < 56u);
      hv[j] = ok ? *(const u16x8*)(vb + ((size_t)dy * 56 + j) * 384) : hz;
    }
#pragma unroll
    for (int t = 0; t < 5; ++t) {
      const int kk = dy * 5 + t;
      const float* gg = &sGG[(kk * 16 + ol) << 4];
      const float4 gm0 = *(const float4*)(gg + ((0 ^ swz) << 2));
      const float4 gm1 = *(const float4*)(gg + ((1 ^ swz) << 2));
      const float4 ga0 = *(const float4*)(gg + ((2 ^ swz) << 2));
      const float4 ga1 = *(const float4*)(gg + ((3 ^ swz) << 2));
      const float a0 = bf2f(sAt[pxl][gl * 25 + kk]);
      const float a1 = bf2f(sAt[pxl + 1][gl * 25 + kk]);
      acc0[0] = fmaf(bf2f(hv[t][0]), fmaf(gm0.x, a0, ga0.x), acc0[0]);
      acc0[1] = fmaf(bf2f(hv[t][1]), fmaf(gm0.y, a0, ga0.y), acc0[1]);
      acc0[2] = fmaf(bf2f(hv[t][2]), fmaf(gm0.z, a0, ga0.z), acc0[2]);
      acc0[3] = fmaf(bf2f(hv[t][3]), fmaf(gm0.w, a0, ga0.w), acc0[3]);
      acc0[4] = fmaf(bf2f(hv[t][4]), fmaf(gm1.x, a0, ga1.x), acc0[4]);
      acc0[5] = fmaf(bf2f(hv[t][5]), fmaf(gm1.y, a0, ga1.y), acc0[5]);
      acc0[6] = fmaf(bf2f(hv[t][6]), fmaf(gm1.z, a0, ga1.z), acc0[6]);
      acc0[7] = fmaf(bf2f(hv[t][7]), fmaf(gm1.w, a0, ga1.w), acc0[7]);
      acc1[0] = fmaf(bf2f(hv[t + 1][0]), fmaf(gm0.x, a1, ga0.x), acc1[0]);
      acc1[1] = fmaf(bf2f(hv[t + 1][1]), fmaf(gm0.y, a1, ga0.y), acc1[1]);
      acc1[2] = fmaf(bf2f(hv[t + 1][2]), fmaf(gm0.z, a1, ga0.z), acc1[2]);
      acc1[3] = fmaf(bf2f(hv[t + 1][3]), fmaf(gm0.w, a1, ga0.w), acc1[3]);
      acc1[4] = fmaf(bf2f(hv[t + 1][4]), fmaf(gm1.x, a1, ga1.x), acc1[4]);
      acc1[5] = fmaf(bf2f(hv[t + 1][5]), fmaf(gm1.y, a1, ga1.y), acc1[5]);
      acc1[6] = fmaf(bf2f(hv[t + 1][6]), fmaf(gm1.z, a1, ga1.z), acc1[6]);
      acc1[7] = fmaf(bf2f(hv[t + 1][7]), fmaf(gm1.w, a1, ga1.w), acc1[7]);
    }
  }

  u16x8 ov0, ov1;
#pragma unroll
  for (int i = 0; i < 8; ++i) { ov0[i] = f2bf(acc0[i]); ov1[i] = f2bf(acc1[i]); }
  *(u16x8*)(outp + (size_t)p0 * 384 + og * 8) = ov0;
  *(u16x8*)(outp + (size_t)(p0 + 1) * 384 + og * 8) = ov1;
}

// ---------------- Kernel D: post GEMM (hi/lo B frags from L2) ----------------
__global__ __launch_bounds__(256) void k_post_mfma(const unsigned short* __restrict__ outp,
                                                   const unsigned short* __restrict__ wpostf,
                                                   const float* __restrict__ b_post,
                                                   float* __restrict__ out) {
  __shared__ unsigned short sA[2][4096];
  const int tid = threadIdx.x;
  const int m0 = blockIdx.x * 128;
  const int yb = blockIdx.y;            // 0..2
  const int lane = tid & 63, wv = tid >> 6;
  const int wr = wv >> 1, wc = wv & 1;

  const floatx4 fz = {0.f, 0.f, 0.f, 0.f};
  floatx4 acc[4][4];
#pragma unroll
  for (int i = 0; i < 4; ++i)
#pragma unroll
    for (int j = 0; j < 4; ++j) acc[i][j] = fz;

  stage128x32(outp + (size_t)m0 * 384, 384, sA[0], tid);
  const unsigned short* bbase = wpostf + (size_t)(yb * 8 + wc * 4) * 6144 + lane * 8;

  int cur = 0;
#pragma unroll 1
  for (int s = 0; s < 12; ++s) {
    short8 bh[4], bl[4];
#pragma unroll
    for (int nf = 0; nf < 4; ++nf) {
      bh[nf] = *(const short8*)(bbase + (size_t)s * 512 + nf * 6144);
      bl[nf] = *(const short8*)(bbase + (size_t)s * 512 + nf * 6144 + 147456);
    }
    __syncthreads();
    if (s < 11) stage128x32(outp + (size_t)m0 * 384 + (s + 1) * 32, 384, sA[cur ^ 1], tid);
    short8 a[4];
#pragma unroll
    for (int mf = 0; mf < 4; ++mf)
      a[mf] = *(const short8*)&sA[cur][(wr * 64 + mf * 16 + (lane & 15)) * 32 + (lane >> 4) * 8];
#pragma unroll
    for (int mf = 0; mf < 4; ++mf)
#pragma unroll
      for (int nf = 0; nf < 4; ++nf) {
        acc[mf][nf] = __builtin_amdgcn_mfma_f32_16x16x32_bf16(a[mf], bh[nf], acc[mf][nf], 0, 0, 0);
        acc[mf][nf] = __builtin_amdgcn_mfma_f32_16x16x32_bf16(a[mf], bl[nf], acc[mf][nf], 0, 0, 0);
      }
    cur ^= 1;
  }

#pragma unroll
  for (int mf = 0; mf < 4; ++mf)
#pragma unroll
    for (int nf = 0; nf < 4; ++nf) {
      const int col = yb * 128 + wc * 64 + nf * 16 + (lane & 15);
      const float bias = b_post[col];
#pragma unroll
      for (int j = 0; j < 4; ++j) {
        const int row = m0 + wr * 64 + mf * 16 + (lane >> 4) * 4 + j;
        out[(size_t)row * 384 + col] = acc[mf][nf][j] + bias;
      }
    }
}

extern "C" void kernel_launch(void* const* d_in, const int* in_sizes, int n_in,
                              void* d_out, int out_size, void* d_ws, size_t ws_size,
                              hipStream_t stream) {
  const float* x      = (const float*)d_in[0];
  const float* w_pre  = (const float*)d_in[1];
  const float* w1     = (const float*)d_in[2];
  const float* b1     = (const float*)d_in[3];
  const float* w2     = (const float*)d_in[4];
  const float* b2     = (const float*)d_in[5];
  const float* gh     = (const float*)d_in[6];
  const float* w_post = (const float*)d_in[7];
  const float* b_post = (const float*)d_in[8];
  float* out = (float*)d_out;

  char* ws = (char*)d_ws;
  unsigned short* xb     = (unsigned short*)ws;
  unsigned short* hm     = (unsigned short*)ws;
  unsigned short* w1mp   = (unsigned short*)(ws + 25690112);
  unsigned short* w2f    = (unsigned short*)(ws + 25903104);    // 155,648 B
  unsigned short* outp   = (unsigned short*)ws;
  unsigned short* had    = (unsigned short*)(ws + 38535168);
  float*          ggp    = (float*)(ws + 38535168);             // reuses dead `had`
  unsigned short* v      = (unsigned short*)(ws + 64225280);
  unsigned short* attn   = (unsigned short*)(ws + 102760448);
  unsigned short* wpbf   = (unsigned short*)(ws + 132866048);   // 688,128 B (56 groups)
  unsigned short* wpostf = (unsigned short*)(ws + 133554176);   // 589,824 B (hi+lo)

  k_cvt<<<dim3(2048), dim3(256), 0, stream>>>(x, xb, 19267584 / 8);
  k_wfrag<<<dim3(1344), dim3(256), 0, stream>>>(w_pre, wpbf, 344064);
  k_wpostf<<<dim3(1152), dim3(256), 0, stream>>>(w_post, wpostf);

  k_pre_qk<<<dim3(392, 2), dim3(256), 0, stream>>>(xb, wpbf, had);
  k_pre_v<<<dim3(392, 3), dim3(256), 0, stream>>>(xb, wpbf, v);

  // xb dead now; pack small weights into R0 slack
  k_w1mpack<<<dim3(416), dim3(256), 0, stream>>>(w1, w1mp);
  k_w2frag<<<dim3(304), dim3(256), 0, stream>>>(w2, w2f);

  k_conv_mfma<<<dim3(784, 2), dim3(256), 0, stream>>>(had, w1mp, b1, hm);
  // had dead now; ggp reuses its storage (outside R0, so k_elsa's outp writes
  // cannot clobber it)
  k_ggpack<<<dim3(75), dim3(256), 0, stream>>>(gh, ggp);
  k_1x1s<<<dim3(784), dim3(256), 0, stream>>>(hm, w2f, b2, attn);
  k_elsa<<<dim3(784, 3), dim3(512), 0, stream>>>(v, attn, ggp, outp);
  k_post_mfma<<<dim3(392, 3), dim3(256), 0, stream>>>(outp, wpostf, b_post, out);
}

// Round 19
// 278.921 us; speedup vs baseline: 1.0605x; 1.0094x over previous
//
#include <hip/hip_runtime.h>
#include <hip/hip_bf16.h>

#define NPX 50176
#define SCALE 0.17677669529663687f

typedef __attribute__((ext_vector_type(8))) short short8;
typedef __attribute__((ext_vector_type(4))) float floatx4;
using u16x8 = __attribute__((ext_vector_type(8))) unsigned short;

static __device__ __forceinline__ float bf2f(unsigned short u) {
  union { unsigned int i; float f; } c; c.i = ((unsigned int)u) << 16; return c.f;
}
static __device__ __forceinline__ unsigned short f2bf(float f) {
  union { float f; unsigned int i; } c; c.f = f;
  unsigned int u = c.i;
  u += 0x7fffu + ((u >> 16) & 1u);
  return (unsigned short)(u >> 16);
}

static __device__ __forceinline__ void gl_lds16(const unsigned short* g, unsigned short* l) {
  __builtin_amdgcn_global_load_lds(
      (const __attribute__((address_space(1))) void*)g,
      (__attribute__((address_space(3))) void*)l, 16, 0, 0);
}

// stage a 128x32 bf16 tile (row stride ldK elems) into linear LDS [128][32] (4096 u16)
static __device__ __forceinline__ void stage128x32(const unsigned short* g, int ldK,
                                                   unsigned short* lds, int tid) {
  const int wv = tid >> 6, lane = tid & 63;
#pragma unroll
  for (int i = 0; i < 2; ++i) {
    const int ci = i * 4 + wv;
    const int row = ci * 16 + (lane >> 2);
    const int col = (lane & 3) * 8;
    gl_lds16(g + (size_t)row * ldK + col, lds + ci * 512);
  }
}

// stage a 64x32 bf16 tile into linear LDS [64][32] (2048 u16); 1 granule/thread
static __device__ __forceinline__ void stage64x32(const unsigned short* g, int ldK,
                                                  unsigned short* lds, int tid) {
  const int row = tid >> 2;
  const int col = (tid & 3) * 8;
  gl_lds16(g + (size_t)row * ldK + col, lds + tid * 8);
}

// ---------------- converters / packers ----------------
__global__ __launch_bounds__(256) void k_cvt(const float* __restrict__ src,
                                             unsigned short* __restrict__ dst, int n8) {
  int i = blockIdx.x * 256 + threadIdx.x;
  const int stride = gridDim.x * 256;
  for (; i < n8; i += stride) {
    float4 f0 = *(const float4*)(src + (size_t)i * 8);
    float4 f1 = *(const float4*)(src + (size_t)i * 8 + 4);
    u16x8 o;
    o[0] = f2bf(f0.x); o[1] = f2bf(f0.y); o[2] = f2bf(f0.z); o[3] = f2bf(f0.w);
    o[4] = f2bf(f1.x); o[5] = f2bf(f1.y); o[6] = f2bf(f1.z); o[7] = f2bf(f1.w);
    *(u16x8*)(dst + (size_t)i * 8) = o;
  }
}

// fragment-pack a [ncols x 384] f32 row-major matrix into [g][s][lane][8] bf16
__global__ __launch_bounds__(256) void k_wfrag(const float* __restrict__ w,
                                               unsigned short* __restrict__ dst, int ntot) {
  int idx = blockIdx.x * 256 + threadIdx.x;
  if (idx < ntot) {
    int e = idx & 7;
    int lane = (idx >> 3) & 63;
    int s = (idx >> 9) % 12;
    int g = (idx >> 9) / 12;
    int col = g * 16 + (lane & 15);
    int k = s * 32 + (lane >> 4) * 8 + e;
    dst[idx] = f2bf(w[(size_t)col * 384 + k]);
  }
}

// fragment-pack w_post into hi/lo split: dst[h][g 24][s 12][lane][8]
__global__ __launch_bounds__(256) void k_wpostf(const float* __restrict__ w,
                                                unsigned short* __restrict__ dst) {
  int idx = blockIdx.x * 256 + threadIdx.x;  // 2*24*12*512 = 294912
  if (idx < 294912) {
    int e = idx & 7;
    int lane = (idx >> 3) & 63;
    int s = (idx >> 9) % 12;
    int gh = (idx >> 9) / 12;   // 0..47
    int g = gh % 24, h = gh / 24;
    int col = g * 16 + (lane & 15);
    int k = s * 32 + (lane >> 4) * 8 + e;
    float f = w[(size_t)col * 384 + k];
    unsigned short hi = f2bf(f);
    dst[idx] = (h == 0) ? hi : f2bf(f - bf2f(hi));
  }
}

// w1mp[pairg 16][s 13][lane 64][i 8] bf16, exact 16x16x32 MFMA B-fragment order.
__global__ __launch_bounds__(256) void k_w1mpack(const float* __restrict__ w1,
                                                 unsigned short* __restrict__ w1mp) {
  int idx = blockIdx.x * 256 + threadIdx.x;  // 16*13*64*8 = 106496
  if (idx < 106496) {
    int i = idx & 7;
    int lane = (idx >> 3) & 63;
    int ps = idx >> 9;          // pairg*13 + s
    int s = ps % 13;
    int pairg = ps / 13;
    int n = lane & 15, qq = lane >> 4;
    int k = s * 32 + qq * 8 + i;
    int t = k >> 4, ich = k & 15;
    int o = pairg * 16 + n;
    float v = 0.f;
    if (t < 25 && (ich >> 3) == (n >> 3))
      v = w1[o * 200 + (ich & 7) * 25 + t];
    w1mp[idx] = f2bf(v);
  }
}

// w2f[g 19][s 8][lane][8] bf16, MFMA B-fragment order (cols 300..303 zero)
__global__ __launch_bounds__(256) void k_w2frag(const float* __restrict__ w2,
                                                unsigned short* __restrict__ w2f) {
  int idx = blockIdx.x * 256 + threadIdx.x;  // 19*8*512 = 77824
  if (idx < 77824) {
    int e = idx & 7;
    int lane = (idx >> 3) & 63;
    int s = (idx >> 9) & 7;
    int g = idx >> 12;
    int col = g * 16 + (lane & 15);
    int k = s * 32 + (lane >> 4) * 8 + e;
    w2f[idx] = (col < 300) ? f2bf(w2[(size_t)col * 256 + k]) : (unsigned short)0;
  }
}

// tgg[chunk 3][kk 25][ol 16][e 16] bf16: e<8 = gm[ch og*8+e], e>=8 = ga.
// One 32B row per (tap, octet); ol-stride of 2 granules -> conflict-free b128
// reads (16 ols hit 16 distinct bank-quads), no swizzle needed.
__global__ __launch_bounds__(256) void k_tggpack(const float* __restrict__ gh,
                                                 unsigned short* __restrict__ tgg) {
  int idx = blockIdx.x * 256 + threadIdx.x;  // 3*25*16*16 = 19200
  if (idx < 19200) {
    int e = idx & 15;
    int ol = (idx >> 4) & 15;
    int kk = (idx >> 8) % 25;
    int chunk = (idx >> 8) / 25;
    int c = (chunk * 16 + ol) * 8 + (e & 7);
    float vsrc = (e < 8) ? gh[c * 25 + kk] : gh[9600 + c * 25 + kk];
    tgg[idx] = f2bf(vsrc);
  }
}

// ---------------- Kernel A1: pre GEMM q&k + hadamard (B frags from L2) ----------------
__global__ __launch_bounds__(256) void k_pre_qk(const unsigned short* __restrict__ xb,
                                                const unsigned short* __restrict__ wpbf,
                                                unsigned short* __restrict__ had) {
  __shared__ unsigned short sA[2][4096];
  const int tid = threadIdx.x;
  const int m0 = blockIdx.x * 128;
  const int yb = blockIdx.y;            // 0..1
  const int lane = tid & 63, wv = tid >> 6;
  const int wr = wv >> 1, wc = wv & 1;

  const floatx4 fz = {0.f, 0.f, 0.f, 0.f};
  floatx4 acc0[4][4], acc1[4][4];
#pragma unroll
  for (int i = 0; i < 4; ++i)
#pragma unroll
    for (int j = 0; j < 4; ++j) { acc0[i][j] = fz; acc1[i][j] = fz; }

  stage128x32(xb + (size_t)m0 * 384, 384, sA[0], tid);
  const unsigned short* bbase = wpbf + (size_t)(yb * 8 + wc * 4) * 6144 + lane * 8;

  int cur = 0;
#pragma unroll 1
  for (int s = 0; s < 12; ++s) {
    short8 b0[4], b1[4];
#pragma unroll
    for (int nf = 0; nf < 4; ++nf) {
      b0[nf] = *(const short8*)(bbase + (size_t)s * 512 + nf * 6144);
      b1[nf] = *(const short8*)(bbase + (size_t)s * 512 + nf * 6144 + 98304);
    }
    __syncthreads();
    if (s < 11) stage128x32(xb + (size_t)m0 * 384 + (s + 1) * 32, 384, sA[cur ^ 1], tid);
    short8 a[4];
#pragma unroll
    for (int mf = 0; mf < 4; ++mf)
      a[mf] = *(const short8*)&sA[cur][(wr * 64 + mf * 16 + (lane & 15)) * 32 + (lane >> 4) * 8];
#pragma unroll
    for (int mf = 0; mf < 4; ++mf)
#pragma unroll
      for (int nf = 0; nf < 4; ++nf) {
        acc0[mf][nf] = __builtin_amdgcn_mfma_f32_16x16x32_bf16(a[mf], b0[nf], acc0[mf][nf], 0, 0, 0);
        acc1[mf][nf] = __builtin_amdgcn_mfma_f32_16x16x32_bf16(a[mf], b1[nf], acc1[mf][nf], 0, 0, 0);
      }
    cur ^= 1;
  }

  const int colbase = yb * 128 + wc * 64;
#pragma unroll
  for (int mf = 0; mf < 4; ++mf)
#pragma unroll
    for (int nf = 0; nf < 4; ++nf) {
      const int col = colbase + nf * 16 + (lane & 15);
#pragma unroll
      for (int j = 0; j < 4; ++j) {
        const int row = m0 + wr * 64 + mf * 16 + (lane >> 4) * 4 + j;
        had[(size_t)row * 256 + col] = f2bf(acc0[mf][nf][j] * acc1[mf][nf][j] * SCALE);
      }
    }
}

// ---------------- Kernel A2: pre GEMM v (B frags from L2) ----------------
__global__ __launch_bounds__(256) void k_pre_v(const unsigned short* __restrict__ xb,
                                               const unsigned short* __restrict__ wpbf,
                                               unsigned short* __restrict__ vout) {
  __shared__ unsigned short sA[2][4096];
  const int tid = threadIdx.x;
  const int m0 = blockIdx.x * 128;
  const int yb = blockIdx.y;            // 0..2
  const int lane = tid & 63, wv = tid >> 6;
  const int wr = wv >> 1, wc = wv & 1;

  const floatx4 fz = {0.f, 0.f, 0.f, 0.f};
  floatx4 acc[4][4];
#pragma unroll
  for (int i = 0; i < 4; ++i)
#pragma unroll
    for (int j = 0; j < 4; ++j) acc[i][j] = fz;

  stage128x32(xb + (size_t)m0 * 384, 384, sA[0], tid);
  const unsigned short* bbase = wpbf + (size_t)(32 + yb * 8 + wc * 4) * 6144 + lane * 8;

  int cur = 0;
#pragma unroll 1
  for (int s = 0; s < 12; ++s) {
    short8 b[4];
#pragma unroll
    for (int nf = 0; nf < 4; ++nf)
      b[nf] = *(const short8*)(bbase + (size_t)s * 512 + nf * 6144);
    __syncthreads();
    if (s < 11) stage128x32(xb + (size_t)m0 * 384 + (s + 1) * 32, 384, sA[cur ^ 1], tid);
    short8 a[4];
#pragma unroll
    for (int mf = 0; mf < 4; ++mf)
      a[mf] = *(const short8*)&sA[cur][(wr * 64 + mf * 16 + (lane & 15)) * 32 + (lane >> 4) * 8];
#pragma unroll
    for (int mf = 0; mf < 4; ++mf)
#pragma unroll
      for (int nf = 0; nf < 4; ++nf)
        acc[mf][nf] = __builtin_amdgcn_mfma_f32_16x16x32_bf16(a[mf], b[nf], acc[mf][nf], 0, 0, 0);
    cur ^= 1;
  }

  const int colbase = yb * 128 + wc * 64;
#pragma unroll
  for (int mf = 0; mf < 4; ++mf)
#pragma unroll
    for (int nf = 0; nf < 4; ++nf) {
      const int col = colbase + nf * 16 + (lane & 15);
#pragma unroll
      for (int j = 0; j < 4; ++j) {
        const int row = m0 + wr * 64 + mf * 16 + (lane >> 4) * 4 + j;
        vout[(size_t)row * 384 + col] = f2bf(acc[mf][nf][j]);
      }
    }
}

// ---------------- Kernel B1: grouped 5x5 conv + GELU, MFMA; XCD-swizzled ----------------
__global__ __launch_bounds__(256) void k_conv_mfma(const unsigned short* __restrict__ had,
                                                   const unsigned short* __restrict__ w1mp,
                                                   const float* __restrict__ b1,
                                                   unsigned short* __restrict__ hm) {
  __shared__ unsigned short halo[8 * 288 * 8];  // 36,864 B
  const int tid = threadIdx.x;
  const int lane = tid & 63, wv = tid >> 6;
  const int bxs = (blockIdx.x & 7) * 98 + (blockIdx.x >> 3);
  const int bimg = bxs / 49;
  const int t49 = bxs % 49;
  const int y0 = (t49 / 7) * 8, x0 = (t49 % 7) * 8;
  const int half = blockIdx.y;
  const int c0 = half * 128;

  for (int ii = tid; ii < 2304; ii += 256) {
    const int g16 = ii & 15;       // pair*2 + h
    const int pyx = ii >> 4;       // 0..143
    const int py = pyx / 12, px = pyx % 12;
    const int gy = y0 + py - 2, gx = x0 + px - 2;
    uint4 val = make_uint4(0u, 0u, 0u, 0u);
    if (gy >= 0 && gy < 56 && gx >= 0 && gx < 56)
      val = *(const uint4*)(had + ((size_t)(bimg * 56 + gy) * 56 + gx) * 256 + c0 + g16 * 8);
    *(uint4*)&halo[(size_t)(((g16 >> 1) * 288 + (g16 & 1) * 144 + pyx)) * 8] = val;
  }
  __syncthreads();

  const int r = lane & 15;
  const int q = lane >> 4;
  const int h = q & 1, qh = q >> 1;

  const unsigned short* abase =
      &halo[(size_t)((wv * 2) * 288 + h * 144 + (r >> 3) * 12 + (r & 7)) * 8];
  const unsigned short* wq =
      w1mp + (size_t)((half * 8 + wv * 2) * 13) * 512 + lane * 8;

  const float bs0 = b1[(half * 8 + wv * 2) * 16 + r];
  const float bs1 = b1[(half * 8 + wv * 2 + 1) * 16 + r];

  floatx4 acc[2][4];
#pragma unroll
  for (int mf = 0; mf < 4; ++mf) {
    acc[0][mf] = (floatx4){bs0, bs0, bs0, bs0};
    acc[1][mf] = (floatx4){bs1, bs1, bs1, bs1};
  }

#pragma unroll
  for (int s = 0; s < 13; ++s) {
    const int t0 = 2 * s;
    const int t1 = (t0 + 1 > 24) ? 24 : t0 + 1;
    const int o0 = (t0 / 5) * 12 + (t0 % 5);
    const int o1 = (t1 / 5) * 12 + (t1 % 5);
    const unsigned short* ap = abase + (size_t)(qh ? o1 : o0) * 8;
    const short8 bf0 = *(const short8*)(wq + (size_t)s * 512);
    const short8 bf1 = *(const short8*)(wq + (size_t)(13 + s) * 512);
#pragma unroll
    for (int mf = 0; mf < 4; ++mf) {
      const short8 a0 = *(const short8*)(ap + mf * 192);
      acc[0][mf] = __builtin_amdgcn_mfma_f32_16x16x32_bf16(a0, bf0, acc[0][mf], 0, 0, 0);
    }
#pragma unroll
    for (int mf = 0; mf < 4; ++mf) {
      const short8 a1 = *(const short8*)(ap + 2304 + mf * 192);
      acc[1][mf] = __builtin_amdgcn_mfma_f32_16x16x32_bf16(a1, bf1, acc[1][mf], 0, 0, 0);
    }
  }

#pragma unroll
  for (int pp = 0; pp < 2; ++pp) {
    const int o = (half * 8 + wv * 2 + pp) * 16 + r;
#pragma unroll
    for (int mf = 0; mf < 4; ++mf)
#pragma unroll
      for (int j = 0; j < 4; ++j) {
        const int pix = mf * 16 + q * 4 + j;
        const int pyl = pix >> 3, pxl = pix & 7;
        const size_t gp = (size_t)(bimg * 56 + y0 + pyl) * 56 + (x0 + pxl);
        const float vv = acc[pp][mf][j];
        const float g = 0.5f * vv * (1.0f + erff(vv * 0.70710678118654752f));
        hm[gp * 256 + o] = f2bf(g);
      }
  }
}

// ---------------- Kernel B2: 1x1 GEMM + fused softmax, 64-px blocks ----------------
__global__ __launch_bounds__(256) void k_1x1s(const unsigned short* __restrict__ hm,
                                              const unsigned short* __restrict__ w2f,
                                              const float* __restrict__ b2,
                                              unsigned short* __restrict__ attn) {
  __shared__ unsigned short sA[2][2048];
  __shared__ unsigned short sw[4][16][312];
  const int tid = threadIdx.x;
  const int lane = tid & 63, wv = tid >> 6;
  const int m0 = blockIdx.x * 64;

  const floatx4 fz = {0.f, 0.f, 0.f, 0.f};
  floatx4 acc[19];
#pragma unroll
  for (int nf = 0; nf < 19; ++nf) acc[nf] = fz;

  stage64x32(hm + (size_t)m0 * 256, 256, sA[0], tid);
  const unsigned short* bbase = w2f + lane * 8;
  int cur = 0;
#pragma unroll 1
  for (int s = 0; s < 8; ++s) {
    short8 b[19];
#pragma unroll
    for (int nf = 0; nf < 19; ++nf)
      b[nf] = *(const short8*)(bbase + (size_t)(nf * 8 + s) * 512);
    __syncthreads();
    if (s < 7) stage64x32(hm + (size_t)m0 * 256 + (s + 1) * 32, 256, sA[cur ^ 1], tid);
    const short8 a = *(const short8*)&sA[cur][(wv * 16 + (lane & 15)) * 32 + (lane >> 4) * 8];
#pragma unroll
    for (int nf = 0; nf < 19; ++nf)
      acc[nf] = __builtin_amdgcn_mfma_f32_16x16x32_bf16(a, b[nf], acc[nf], 0, 0, 0);
    cur ^= 1;
  }
  __syncthreads();

#pragma unroll
  for (int nf = 0; nf < 19; ++nf) {
    const int col = nf * 16 + (lane & 15);
    const float bias = (col < 300) ? b2[col] : 0.f;
#pragma unroll
    for (int j = 0; j < 4; ++j) {
      const int row = (lane >> 4) * 4 + j;
      sw[wv][row][col] = f2bf(acc[nf][j] + bias);
    }
  }
  __syncthreads();

#pragma unroll
  for (int t = 0; t < 3; ++t) {
    const int tt = t * 64 + lane;
    const int px = tt & 15, g = tt >> 4;
    unsigned short* srow = &sw[wv][px][g * 25];
    float a2[25];
#pragma unroll
    for (int kk = 0; kk < 25; ++kk) a2[kk] = bf2f(srow[kk]);
    float m = a2[0];
#pragma unroll
    for (int kk = 1; kk < 25; ++kk) m = fmaxf(m, a2[kk]);
    float s = 0.f;
#pragma unroll
    for (int kk = 0; kk < 25; ++kk) { a2[kk] = __expf(a2[kk] - m); s += a2[kk]; }
    const float rr = 1.0f / s;
#pragma unroll
    for (int kk = 0; kk < 25; ++kk) srow[kk] = f2bf(a2[kk] * rr);
  }
  __syncthreads();

  const unsigned short* swl = &sw[0][0][0];
  for (int i = tid; i < 4800; i += 256) {
    const int r = i / 75, c = i % 75;
    const uint2 val = *(const uint2*)(swl + (size_t)r * 312 + c * 4);
    *(uint2*)(attn + (size_t)(m0 + r) * 300 + c * 4) = val;
  }
}

// ---------------- Kernel C: ELSA aggregation v10 (bf16 table) ----------------
// v8 structure + XCD swizzle, with the gm/ga table stored as bf16: 2 b128
// reads per tap instead of 4 (the dominant LDS term), conflict-free layout.
__global__ __launch_bounds__(512) void k_elsa(const unsigned short* __restrict__ v,
                                              const unsigned short* __restrict__ attn,
                                              const unsigned short* __restrict__ tgg,
                                              unsigned short* __restrict__ outp) {
  __shared__ unsigned short sTG[25 * 16 * 16];   // 12,800 B
  __shared__ unsigned short sAt[64][104];        // 13,312 B
  const int tid = threadIdx.x;
  const int chunk = blockIdx.y;
  const int bxs = (blockIdx.x & 7) * 98 + (blockIdx.x >> 3);
  const int pb = bxs * 64;

  {
    const uint4* src = (const uint4*)(tgg + (size_t)chunk * 6400);
    uint4* dst = (uint4*)sTG;
    for (int j = tid; j < 800; j += 512) dst[j] = src[j];
  }
  // stage attn: 64 rows x 100 u16 (this chunk's 4 heads), dense 8B loads
  for (int j = tid; j < 1600; j += 512) {
    const int r = j / 25, c = j % 25;    // c in uint2 units
    const uint2 val = *(const uint2*)(attn + (size_t)(pb + r) * 300 + chunk * 100 + c * 4);
    *(uint2*)&sAt[r][c * 4] = val;
  }
  __syncthreads();

  const int ol = tid & 15;
  const int og = chunk * 16 + ol;
  const int pxi = tid >> 4;           // 0..31
  const int gl = ol >> 2;             // head within chunk
  const int p0 = pb + pxi * 2;
  const int xp = p0 % 56;
  const int yp = (p0 / 56) % 56;
  const int pxl = pxi * 2;

  const unsigned short* __restrict__ vb = v + ((size_t)p0 - 114) * 384 + og * 8;

  float acc0[8], acc1[8];
#pragma unroll
  for (int i = 0; i < 8; ++i) { acc0[i] = 0.f; acc1[i] = 0.f; }

  const u16x8 hz = {0, 0, 0, 0, 0, 0, 0, 0};

#pragma unroll 1
  for (int dy = 0; dy < 5; ++dy) {
    const bool rowok = (unsigned)(yp + dy - 2) < 56u;
    u16x8 hv[6];
#pragma unroll
    for (int j = 0; j < 6; ++j) {
      const bool ok = rowok && ((unsigned)(xp - 2 + j) < 56u);
      hv[j] = ok ? *(const u16x8*)(vb + ((size_t)dy * 56 + j) * 384) : hz;
    }
#pragma unroll
    for (int t = 0; t < 5; ++t) {
      const int kk = dy * 5 + t;
      const unsigned short* tg = &sTG[(kk * 16 + ol) << 4];
      const u16x8 gmv = *(const u16x8*)tg;
      const u16x8 gav = *(const u16x8*)(tg + 8);
      const float a0 = bf2f(sAt[pxl][gl * 25 + kk]);
      const float a1 = bf2f(sAt[pxl + 1][gl * 25 + kk]);
#pragma unroll
      for (int i = 0; i < 8; ++i) {
        const float gm = bf2f(gmv[i]);
        const float ga = bf2f(gav[i]);
        acc0[i] = fmaf(bf2f(hv[t][i]), fmaf(gm, a0, ga), acc0[i]);
        acc1[i] = fmaf(bf2f(hv[t + 1][i]), fmaf(gm, a1, ga), acc1[i]);
      }
    }
  }

  u16x8 ov0, ov1;
#pragma unroll
  for (int i = 0; i < 8; ++i) { ov0[i] = f2bf(acc0[i]); ov1[i] = f2bf(acc1[i]); }
  *(u16x8*)(outp + (size_t)p0 * 384 + og * 8) = ov0;
  *(u16x8*)(outp + (size_t)(p0 + 1) * 384 + og * 8) = ov1;
}

// ---------------- Kernel D: post GEMM (hi/lo B frags from L2) ----------------
__global__ __launch_bounds__(256) void k_post_mfma(const unsigned short* __restrict__ outp,
                                                   const unsigned short* __restrict__ wpostf,
                                                   const float* __restrict__ b_post,
                                                   float* __restrict__ out) {
  __shared__ unsigned short sA[2][4096];
  const int tid = threadIdx.x;
  const int m0 = blockIdx.x * 128;
  const int yb = blockIdx.y;            // 0..2
  const int lane = tid & 63, wv = tid >> 6;
  const int wr = wv >> 1, wc = wv & 1;

  const floatx4 fz = {0.f, 0.f, 0.f, 0.f};
  floatx4 acc[4][4];
#pragma unroll
  for (int i = 0; i < 4; ++i)
#pragma unroll
    for (int j = 0; j < 4; ++j) acc[i][j] = fz;

  stage128x32(outp + (size_t)m0 * 384, 384, sA[0], tid);
  const unsigned short* bbase = wpostf + (size_t)(yb * 8 + wc * 4) * 6144 + lane * 8;

  int cur = 0;
#pragma unroll 1
  for (int s = 0; s < 12; ++s) {
    short8 bh[4], bl[4];
#pragma unroll
    for (int nf = 0; nf < 4; ++nf) {
      bh[nf] = *(const short8*)(bbase + (size_t)s * 512 + nf * 6144);
      bl[nf] = *(const short8*)(bbase + (size_t)s * 512 + nf * 6144 + 147456);
    }
    __syncthreads();
    if (s < 11) stage128x32(outp + (size_t)m0 * 384 + (s + 1) * 32, 384, sA[cur ^ 1], tid);
    short8 a[4];
#pragma unroll
    for (int mf = 0; mf < 4; ++mf)
      a[mf] = *(const short8*)&sA[cur][(wr * 64 + mf * 16 + (lane & 15)) * 32 + (lane >> 4) * 8];
#pragma unroll
    for (int mf = 0; mf < 4; ++mf)
#pragma unroll
      for (int nf = 0; nf < 4; ++nf) {
        acc[mf][nf] = __builtin_amdgcn_mfma_f32_16x16x32_bf16(a[mf], bh[nf], acc[mf][nf], 0, 0, 0);
        acc[mf][nf] = __builtin_amdgcn_mfma_f32_16x16x32_bf16(a[mf], bl[nf], acc[mf][nf], 0, 0, 0);
      }
    cur ^= 1;
  }

#pragma unroll
  for (int mf = 0; mf < 4; ++mf)
#pragma unroll
    for (int nf = 0; nf < 4; ++nf) {
      const int col = yb * 128 + wc * 64 + nf * 16 + (lane & 15);
      const float bias = b_post[col];
#pragma unroll
      for (int j = 0; j < 4; ++j) {
        const int row = m0 + wr * 64 + mf * 16 + (lane >> 4) * 4 + j;
        out[(size_t)row * 384 + col] = acc[mf][nf][j] + bias;
      }
    }
}

extern "C" void kernel_launch(void* const* d_in, const int* in_sizes, int n_in,
                              void* d_out, int out_size, void* d_ws, size_t ws_size,
                              hipStream_t stream) {
  const float* x      = (const float*)d_in[0];
  const float* w_pre  = (const float*)d_in[1];
  const float* w1     = (const float*)d_in[2];
  const float* b1     = (const float*)d_in[3];
  const float* w2     = (const float*)d_in[4];
  const float* b2     = (const float*)d_in[5];
  const float* gh     = (const float*)d_in[6];
  const float* w_post = (const float*)d_in[7];
  const float* b_post = (const float*)d_in[8];
  float* out = (float*)d_out;

  char* ws = (char*)d_ws;
  unsigned short* xb     = (unsigned short*)ws;
  unsigned short* hm     = (unsigned short*)ws;
  unsigned short* w1mp   = (unsigned short*)(ws + 25690112);
  unsigned short* w2f    = (unsigned short*)(ws + 25903104);    // 155,648 B
  unsigned short* outp   = (unsigned short*)ws;
  unsigned short* had    = (unsigned short*)(ws + 38535168);
  unsigned short* tgg    = (unsigned short*)(ws + 38535168);    // reuses dead `had`
  unsigned short* v      = (unsigned short*)(ws + 64225280);
  unsigned short* attn   = (unsigned short*)(ws + 102760448);
  unsigned short* wpbf   = (unsigned short*)(ws + 132866048);   // 688,128 B (56 groups)
  unsigned short* wpostf = (unsigned short*)(ws + 133554176);   // 589,824 B (hi+lo)

  k_cvt<<<dim3(2048), dim3(256), 0, stream>>>(x, xb, 19267584 / 8);
  k_wfrag<<<dim3(1344), dim3(256), 0, stream>>>(w_pre, wpbf, 344064);
  k_wpostf<<<dim3(1152), dim3(256), 0, stream>>>(w_post, wpostf);

  k_pre_qk<<<dim3(392, 2), dim3(256), 0, stream>>>(xb, wpbf, had);
  k_pre_v<<<dim3(392, 3), dim3(256), 0, stream>>>(xb, wpbf, v);

  // xb dead now; pack small weights into R0 slack
  k_w1mpack<<<dim3(416), dim3(256), 0, stream>>>(w1, w1mp);
  k_w2frag<<<dim3(304), dim3(256), 0, stream>>>(w2, w2f);

  k_conv_mfma<<<dim3(784, 2), dim3(256), 0, stream>>>(had, w1mp, b1, hm);
  // had dead now; tgg reuses its storage (outside R0, so k_elsa's outp writes
  // cannot clobber it)
  k_tggpack<<<dim3(75), dim3(256), 0, stream>>>(gh, tgg);
  k_1x1s<<<dim3(784), dim3(256), 0, stream>>>(hm, w2f, b2, attn);
  k_elsa<<<dim3(784, 3), dim3(512), 0, stream>>>(v, attn, tgg, outp);
  k_post_mfma<<<dim3(392, 3), dim3(256), 0, stream>>>(outp, wpostf, b_post, out);
}

// Round 20
// 273.755 us; speedup vs baseline: 1.0805x; 1.0189x over previous
//
#include <hip/hip_runtime.h>
#include <hip/hip_bf16.h>

#define NPX 50176
#define SCALE 0.17677669529663687f

typedef __attribute__((ext_vector_type(8))) short short8;
typedef __attribute__((ext_vector_type(4))) float floatx4;
typedef __attribute__((ext_vector_type(2))) float floatx2;
using u16x8 = __attribute__((ext_vector_type(8))) unsigned short;

static __device__ __forceinline__ float bf2f(unsigned short u) {
  union { unsigned int i; float f; } c; c.i = ((unsigned int)u) << 16; return c.f;
}
static __device__ __forceinline__ unsigned short f2bf(float f) {
  union { float f; unsigned int i; } c; c.f = f;
  unsigned int u = c.i;
  u += 0x7fffu + ((u >> 16) & 1u);
  return (unsigned short)(u >> 16);
}

// two independent f32 FMAs in one instruction (CDNA packed math)
static __device__ __forceinline__ floatx2 pk_fma(floatx2 a, floatx2 b, floatx2 c) {
  floatx2 d;
  asm("v_pk_fma_f32 %0, %1, %2, %3" : "=v"(d) : "v"(a), "v"(b), "v"(c));
  return d;
}

static __device__ __forceinline__ void gl_lds16(const unsigned short* g, unsigned short* l) {
  __builtin_amdgcn_global_load_lds(
      (const __attribute__((address_space(1))) void*)g,
      (__attribute__((address_space(3))) void*)l, 16, 0, 0);
}

// stage a 128x32 bf16 tile (row stride ldK elems) into linear LDS [128][32] (4096 u16)
static __device__ __forceinline__ void stage128x32(const unsigned short* g, int ldK,
                                                   unsigned short* lds, int tid) {
  const int wv = tid >> 6, lane = tid & 63;
#pragma unroll
  for (int i = 0; i < 2; ++i) {
    const int ci = i * 4 + wv;
    const int row = ci * 16 + (lane >> 2);
    const int col = (lane & 3) * 8;
    gl_lds16(g + (size_t)row * ldK + col, lds + ci * 512);
  }
}

// stage a 64x32 bf16 tile into linear LDS [64][32] (2048 u16); 1 granule/thread
static __device__ __forceinline__ void stage64x32(const unsigned short* g, int ldK,
                                                  unsigned short* lds, int tid) {
  const int row = tid >> 2;
  const int col = (tid & 3) * 8;
  gl_lds16(g + (size_t)row * ldK + col, lds + tid * 8);
}

// ---------------- converters / packers ----------------
__global__ __launch_bounds__(256) void k_cvt(const float* __restrict__ src,
                                             unsigned short* __restrict__ dst, int n8) {
  int i = blockIdx.x * 256 + threadIdx.x;
  const int stride = gridDim.x * 256;
  for (; i < n8; i += stride) {
    float4 f0 = *(const float4*)(src + (size_t)i * 8);
    float4 f1 = *(const float4*)(src + (size_t)i * 8 + 4);
    u16x8 o;
    o[0] = f2bf(f0.x); o[1] = f2bf(f0.y); o[2] = f2bf(f0.z); o[3] = f2bf(f0.w);
    o[4] = f2bf(f1.x); o[5] = f2bf(f1.y); o[6] = f2bf(f1.z); o[7] = f2bf(f1.w);
    *(u16x8*)(dst + (size_t)i * 8) = o;
  }
}

// fragment-pack a [ncols x 384] f32 row-major matrix into [g][s][lane][8] bf16
__global__ __launch_bounds__(256) void k_wfrag(const float* __restrict__ w,
                                               unsigned short* __restrict__ dst, int ntot) {
  int idx = blockIdx.x * 256 + threadIdx.x;
  if (idx < ntot) {
    int e = idx & 7;
    int lane = (idx >> 3) & 63;
    int s = (idx >> 9) % 12;
    int g = (idx >> 9) / 12;
    int col = g * 16 + (lane & 15);
    int k = s * 32 + (lane >> 4) * 8 + e;
    dst[idx] = f2bf(w[(size_t)col * 384 + k]);
  }
}

// fragment-pack w_post into hi/lo split: dst[h][g 24][s 12][lane][8]
__global__ __launch_bounds__(256) void k_wpostf(const float* __restrict__ w,
                                                unsigned short* __restrict__ dst) {
  int idx = blockIdx.x * 256 + threadIdx.x;  // 2*24*12*512 = 294912
  if (idx < 294912) {
    int e = idx & 7;
    int lane = (idx >> 3) & 63;
    int s = (idx >> 9) % 12;
    int gh = (idx >> 9) / 12;   // 0..47
    int g = gh % 24, h = gh / 24;
    int col = g * 16 + (lane & 15);
    int k = s * 32 + (lane >> 4) * 8 + e;
    float f = w[(size_t)col * 384 + k];
    unsigned short hi = f2bf(f);
    dst[idx] = (h == 0) ? hi : f2bf(f - bf2f(hi));
  }
}

// w1mp[pairg 16][s 13][lane 64][i 8] bf16, exact 16x16x32 MFMA B-fragment order.
__global__ __launch_bounds__(256) void k_w1mpack(const float* __restrict__ w1,
                                                 unsigned short* __restrict__ w1mp) {
  int idx = blockIdx.x * 256 + threadIdx.x;  // 16*13*64*8 = 106496
  if (idx < 106496) {
    int i = idx & 7;
    int lane = (idx >> 3) & 63;
    int ps = idx >> 9;          // pairg*13 + s
    int s = ps % 13;
    int pairg = ps / 13;
    int n = lane & 15, qq = lane >> 4;
    int k = s * 32 + qq * 8 + i;
    int t = k >> 4, ich = k & 15;
    int o = pairg * 16 + n;
    float v = 0.f;
    if (t < 25 && (ich >> 3) == (n >> 3))
      v = w1[o * 200 + (ich & 7) * 25 + t];
    w1mp[idx] = f2bf(v);
  }
}

// w2f[g 19][s 8][lane][8] bf16, MFMA B-fragment order (cols 300..303 zero)
__global__ __launch_bounds__(256) void k_w2frag(const float* __restrict__ w2,
                                                unsigned short* __restrict__ w2f) {
  int idx = blockIdx.x * 256 + threadIdx.x;  // 19*8*512 = 77824
  if (idx < 77824) {
    int e = idx & 7;
    int lane = (idx >> 3) & 63;
    int s = (idx >> 9) & 7;
    int g = idx >> 12;
    int col = g * 16 + (lane & 15);
    int k = s * 32 + (lane >> 4) * 8 + e;
    w2f[idx] = (col < 300) ? f2bf(w2[(size_t)col * 256 + k]) : (unsigned short)0;
  }
}

// tgg[chunk 3][kk 25][ol 16][e 16] bf16: e<8 = gm[ch og*8+e], e>=8 = ga.
__global__ __launch_bounds__(256) void k_tggpack(const float* __restrict__ gh,
                                                 unsigned short* __restrict__ tgg) {
  int idx = blockIdx.x * 256 + threadIdx.x;  // 3*25*16*16 = 19200
  if (idx < 19200) {
    int e = idx & 15;
    int ol = (idx >> 4) & 15;
    int kk = (idx >> 8) % 25;
    int chunk = (idx >> 8) / 25;
    int c = (chunk * 16 + ol) * 8 + (e & 7);
    float vsrc = (e < 8) ? gh[c * 25 + kk] : gh[9600 + c * 25 + kk];
    tgg[idx] = f2bf(vsrc);
  }
}

// ---------------- Kernel A1: pre GEMM q&k + hadamard (B frags from L2) ----------------
__global__ __launch_bounds__(256) void k_pre_qk(const unsigned short* __restrict__ xb,
                                                const unsigned short* __restrict__ wpbf,
                                                unsigned short* __restrict__ had) {
  __shared__ unsigned short sA[2][4096];
  const int tid = threadIdx.x;
  const int m0 = blockIdx.x * 128;
  const int yb = blockIdx.y;            // 0..1
  const int lane = tid & 63, wv = tid >> 6;
  const int wr = wv >> 1, wc = wv & 1;

  const floatx4 fz = {0.f, 0.f, 0.f, 0.f};
  floatx4 acc0[4][4], acc1[4][4];
#pragma unroll
  for (int i = 0; i < 4; ++i)
#pragma unroll
    for (int j = 0; j < 4; ++j) { acc0[i][j] = fz; acc1[i][j] = fz; }

  stage128x32(xb + (size_t)m0 * 384, 384, sA[0], tid);
  const unsigned short* bbase = wpbf + (size_t)(yb * 8 + wc * 4) * 6144 + lane * 8;

  int cur = 0;
#pragma unroll 1
  for (int s = 0; s < 12; ++s) {
    short8 b0[4], b1[4];
#pragma unroll
    for (int nf = 0; nf < 4; ++nf) {
      b0[nf] = *(const short8*)(bbase + (size_t)s * 512 + nf * 6144);
      b1[nf] = *(const short8*)(bbase + (size_t)s * 512 + nf * 6144 + 98304);
    }
    __syncthreads();
    if (s < 11) stage128x32(xb + (size_t)m0 * 384 + (s + 1) * 32, 384, sA[cur ^ 1], tid);
    short8 a[4];
#pragma unroll
    for (int mf = 0; mf < 4; ++mf)
      a[mf] = *(const short8*)&sA[cur][(wr * 64 + mf * 16 + (lane & 15)) * 32 + (lane >> 4) * 8];
#pragma unroll
    for (int mf = 0; mf < 4; ++mf)
#pragma unroll
      for (int nf = 0; nf < 4; ++nf) {
        acc0[mf][nf] = __builtin_amdgcn_mfma_f32_16x16x32_bf16(a[mf], b0[nf], acc0[mf][nf], 0, 0, 0);
        acc1[mf][nf] = __builtin_amdgcn_mfma_f32_16x16x32_bf16(a[mf], b1[nf], acc1[mf][nf], 0, 0, 0);
      }
    cur ^= 1;
  }

  const int colbase = yb * 128 + wc * 64;
#pragma unroll
  for (int mf = 0; mf < 4; ++mf)
#pragma unroll
    for (int nf = 0; nf < 4; ++nf) {
      const int col = colbase + nf * 16 + (lane & 15);
#pragma unroll
      for (int j = 0; j < 4; ++j) {
        const int row = m0 + wr * 64 + mf * 16 + (lane >> 4) * 4 + j;
        had[(size_t)row * 256 + col] = f2bf(acc0[mf][nf][j] * acc1[mf][nf][j] * SCALE);
      }
    }
}

// ---------------- Kernel A2: pre GEMM v (B frags from L2) ----------------
__global__ __launch_bounds__(256) void k_pre_v(const unsigned short* __restrict__ xb,
                                               const unsigned short* __restrict__ wpbf,
                                               unsigned short* __restrict__ vout) {
  __shared__ unsigned short sA[2][4096];
  const int tid = threadIdx.x;
  const int m0 = blockIdx.x * 128;
  const int yb = blockIdx.y;            // 0..2
  const int lane = tid & 63, wv = tid >> 6;
  const int wr = wv >> 1, wc = wv & 1;

  const floatx4 fz = {0.f, 0.f, 0.f, 0.f};
  floatx4 acc[4][4];
#pragma unroll
  for (int i = 0; i < 4; ++i)
#pragma unroll
    for (int j = 0; j < 4; ++j) acc[i][j] = fz;

  stage128x32(xb + (size_t)m0 * 384, 384, sA[0], tid);
  const unsigned short* bbase = wpbf + (size_t)(32 + yb * 8 + wc * 4) * 6144 + lane * 8;

  int cur = 0;
#pragma unroll 1
  for (int s = 0; s < 12; ++s) {
    short8 b[4];
#pragma unroll
    for (int nf = 0; nf < 4; ++nf)
      b[nf] = *(const short8*)(bbase + (size_t)s * 512 + nf * 6144);
    __syncthreads();
    if (s < 11) stage128x32(xb + (size_t)m0 * 384 + (s + 1) * 32, 384, sA[cur ^ 1], tid);
    short8 a[4];
#pragma unroll
    for (int mf = 0; mf < 4; ++mf)
      a[mf] = *(const short8*)&sA[cur][(wr * 64 + mf * 16 + (lane & 15)) * 32 + (lane >> 4) * 8];
#pragma unroll
    for (int mf = 0; mf < 4; ++mf)
#pragma unroll
      for (int nf = 0; nf < 4; ++nf)
        acc[mf][nf] = __builtin_amdgcn_mfma_f32_16x16x32_bf16(a[mf], b[nf], acc[mf][nf], 0, 0, 0);
    cur ^= 1;
  }

  const int colbase = yb * 128 + wc * 64;
#pragma unroll
  for (int mf = 0; mf < 4; ++mf)
#pragma unroll
    for (int nf = 0; nf < 4; ++nf) {
      const int col = colbase + nf * 16 + (lane & 15);
#pragma unroll
      for (int j = 0; j < 4; ++j) {
        const int row = m0 + wr * 64 + mf * 16 + (lane >> 4) * 4 + j;
        vout[(size_t)row * 384 + col] = f2bf(acc[mf][nf][j]);
      }
    }
}

// ---------------- Kernel B1: grouped 5x5 conv + GELU, MFMA; XCD-swizzled ----------------
__global__ __launch_bounds__(256) void k_conv_mfma(const unsigned short* __restrict__ had,
                                                   const unsigned short* __restrict__ w1mp,
                                                   const float* __restrict__ b1,
                                                   unsigned short* __restrict__ hm) {
  __shared__ unsigned short halo[8 * 288 * 8];  // 36,864 B
  const int tid = threadIdx.x;
  const int lane = tid & 63, wv = tid >> 6;
  const int bxs = (blockIdx.x & 7) * 98 + (blockIdx.x >> 3);
  const int bimg = bxs / 49;
  const int t49 = bxs % 49;
  const int y0 = (t49 / 7) * 8, x0 = (t49 % 7) * 8;
  const int half = blockIdx.y;
  const int c0 = half * 128;

  for (int ii = tid; ii < 2304; ii += 256) {
    const int g16 = ii & 15;       // pair*2 + h
    const int pyx = ii >> 4;       // 0..143
    const int py = pyx / 12, px = pyx % 12;
    const int gy = y0 + py - 2, gx = x0 + px - 2;
    uint4 val = make_uint4(0u, 0u, 0u, 0u);
    if (gy >= 0 && gy < 56 && gx >= 0 && gx < 56)
      val = *(const uint4*)(had + ((size_t)(bimg * 56 + gy) * 56 + gx) * 256 + c0 + g16 * 8);
    *(uint4*)&halo[(size_t)(((g16 >> 1) * 288 + (g16 & 1) * 144 + pyx)) * 8] = val;
  }
  __syncthreads();

  const int r = lane & 15;
  const int q = lane >> 4;
  const int h = q & 1, qh = q >> 1;

  const unsigned short* abase =
      &halo[(size_t)((wv * 2) * 288 + h * 144 + (r >> 3) * 12 + (r & 7)) * 8];
  const unsigned short* wq =
      w1mp + (size_t)((half * 8 + wv * 2) * 13) * 512 + lane * 8;

  const float bs0 = b1[(half * 8 + wv * 2) * 16 + r];
  const float bs1 = b1[(half * 8 + wv * 2 + 1) * 16 + r];

  floatx4 acc[2][4];
#pragma unroll
  for (int mf = 0; mf < 4; ++mf) {
    acc[0][mf] = (floatx4){bs0, bs0, bs0, bs0};
    acc[1][mf] = (floatx4){bs1, bs1, bs1, bs1};
  }

#pragma unroll
  for (int s = 0; s < 13; ++s) {
    const int t0 = 2 * s;
    const int t1 = (t0 + 1 > 24) ? 24 : t0 + 1;
    const int o0 = (t0 / 5) * 12 + (t0 % 5);
    const int o1 = (t1 / 5) * 12 + (t1 % 5);
    const unsigned short* ap = abase + (size_t)(qh ? o1 : o0) * 8;
    const short8 bf0 = *(const short8*)(wq + (size_t)s * 512);
    const short8 bf1 = *(const short8*)(wq + (size_t)(13 + s) * 512);
#pragma unroll
    for (int mf = 0; mf < 4; ++mf) {
      const short8 a0 = *(const short8*)(ap + mf * 192);
      acc[0][mf] = __builtin_amdgcn_mfma_f32_16x16x32_bf16(a0, bf0, acc[0][mf], 0, 0, 0);
    }
#pragma unroll
    for (int mf = 0; mf < 4; ++mf) {
      const short8 a1 = *(const short8*)(ap + 2304 + mf * 192);
      acc[1][mf] = __builtin_amdgcn_mfma_f32_16x16x32_bf16(a1, bf1, acc[1][mf], 0, 0, 0);
    }
  }

#pragma unroll
  for (int pp = 0; pp < 2; ++pp) {
    const int o = (half * 8 + wv * 2 + pp) * 16 + r;
#pragma unroll
    for (int mf = 0; mf < 4; ++mf)
#pragma unroll
      for (int j = 0; j < 4; ++j) {
        const int pix = mf * 16 + q * 4 + j;
        const int pyl = pix >> 3, pxl = pix & 7;
        const size_t gp = (size_t)(bimg * 56 + y0 + pyl) * 56 + (x0 + pxl);
        const float vv = acc[pp][mf][j];
        const float g = 0.5f * vv * (1.0f + erff(vv * 0.70710678118654752f));
        hm[gp * 256 + o] = f2bf(g);
      }
  }
}

// ---------------- Kernel B2: 1x1 GEMM + fused softmax, 64-px blocks ----------------
__global__ __launch_bounds__(256) void k_1x1s(const unsigned short* __restrict__ hm,
                                              const unsigned short* __restrict__ w2f,
                                              const float* __restrict__ b2,
                                              unsigned short* __restrict__ attn) {
  __shared__ unsigned short sA[2][2048];
  __shared__ unsigned short sw[4][16][312];
  const int tid = threadIdx.x;
  const int lane = tid & 63, wv = tid >> 6;
  const int m0 = blockIdx.x * 64;

  const floatx4 fz = {0.f, 0.f, 0.f, 0.f};
  floatx4 acc[19];
#pragma unroll
  for (int nf = 0; nf < 19; ++nf) acc[nf] = fz;

  stage64x32(hm + (size_t)m0 * 256, 256, sA[0], tid);
  const unsigned short* bbase = w2f + lane * 8;
  int cur = 0;
#pragma unroll 1
  for (int s = 0; s < 8; ++s) {
    short8 b[19];
#pragma unroll
    for (int nf = 0; nf < 19; ++nf)
      b[nf] = *(const short8*)(bbase + (size_t)(nf * 8 + s) * 512);
    __syncthreads();
    if (s < 7) stage64x32(hm + (size_t)m0 * 256 + (s + 1) * 32, 256, sA[cur ^ 1], tid);
    const short8 a = *(const short8*)&sA[cur][(wv * 16 + (lane & 15)) * 32 + (lane >> 4) * 8];
#pragma unroll
    for (int nf = 0; nf < 19; ++nf)
      acc[nf] = __builtin_amdgcn_mfma_f32_16x16x32_bf16(a, b[nf], acc[nf], 0, 0, 0);
    cur ^= 1;
  }
  __syncthreads();

#pragma unroll
  for (int nf = 0; nf < 19; ++nf) {
    const int col = nf * 16 + (lane & 15);
    const float bias = (col < 300) ? b2[col] : 0.f;
#pragma unroll
    for (int j = 0; j < 4; ++j) {
      const int row = (lane >> 4) * 4 + j;
      sw[wv][row][col] = f2bf(acc[nf][j] + bias);
    }
  }
  __syncthreads();

#pragma unroll
  for (int t = 0; t < 3; ++t) {
    const int tt = t * 64 + lane;
    const int px = tt & 15, g = tt >> 4;
    unsigned short* srow = &sw[wv][px][g * 25];
    float a2[25];
#pragma unroll
    for (int kk = 0; kk < 25; ++kk) a2[kk] = bf2f(srow[kk]);
    float m = a2[0];
#pragma unroll
    for (int kk = 1; kk < 25; ++kk) m = fmaxf(m, a2[kk]);
    float s = 0.f;
#pragma unroll
    for (int kk = 0; kk < 25; ++kk) { a2[kk] = __expf(a2[kk] - m); s += a2[kk]; }
    const float rr = 1.0f / s;
#pragma unroll
    for (int kk = 0; kk < 25; ++kk) srow[kk] = f2bf(a2[kk] * rr);
  }
  __syncthreads();

  const unsigned short* swl = &sw[0][0][0];
  for (int i = tid; i < 4800; i += 256) {
    const int r = i / 75, c = i % 75;
    const uint2 val = *(const uint2*)(swl + (size_t)r * 312 + c * 4);
    *(uint2*)(attn + (size_t)(m0 + r) * 300 + c * 4) = val;
  }
}

// ---------------- Kernel C: ELSA aggregation v11 (bf16 table + pk_fma) ----------------
// v10 structure with the inner loop on v_pk_fma_f32: 16 packed FMAs per tap
// instead of 32 scalar (element values and op order identical -> same absmax).
__global__ __launch_bounds__(512) void k_elsa(const unsigned short* __restrict__ v,
                                              const unsigned short* __restrict__ attn,
                                              const unsigned short* __restrict__ tgg,
                                              unsigned short* __restrict__ outp) {
  __shared__ unsigned short sTG[25 * 16 * 16];   // 12,800 B
  __shared__ unsigned short sAt[64][104];        // 13,312 B
  const int tid = threadIdx.x;
  const int chunk = blockIdx.y;
  const int bxs = (blockIdx.x & 7) * 98 + (blockIdx.x >> 3);
  const int pb = bxs * 64;

  {
    const uint4* src = (const uint4*)(tgg + (size_t)chunk * 6400);
    uint4* dst = (uint4*)sTG;
    for (int j = tid; j < 800; j += 512) dst[j] = src[j];
  }
  for (int j = tid; j < 1600; j += 512) {
    const int r = j / 25, c = j % 25;
    const uint2 val = *(const uint2*)(attn + (size_t)(pb + r) * 300 + chunk * 100 + c * 4);
    *(uint2*)&sAt[r][c * 4] = val;
  }
  __syncthreads();

  const int ol = tid & 15;
  const int og = chunk * 16 + ol;
  const int pxi = tid >> 4;           // 0..31
  const int gl = ol >> 2;             // head within chunk
  const int p0 = pb + pxi * 2;
  const int xp = p0 % 56;
  const int yp = (p0 / 56) % 56;
  const int pxl = pxi * 2;

  const unsigned short* __restrict__ vb = v + ((size_t)p0 - 114) * 384 + og * 8;

  floatx2 acc0[4], acc1[4];
#pragma unroll
  for (int i = 0; i < 4; ++i) {
    acc0[i] = (floatx2){0.f, 0.f};
    acc1[i] = (floatx2){0.f, 0.f};
  }

  const u16x8 hz = {0, 0, 0, 0, 0, 0, 0, 0};

#pragma unroll 1
  for (int dy = 0; dy < 5; ++dy) {
    const bool rowok = (unsigned)(yp + dy - 2) < 56u;
    u16x8 hv[6];
#pragma unroll
    for (int j = 0; j < 6; ++j) {
      const bool ok = rowok && ((unsigned)(xp - 2 + j) < 56u);
      hv[j] = ok ? *(const u16x8*)(vb + ((size_t)dy * 56 + j) * 384) : hz;
    }
#pragma unroll
    for (int t = 0; t < 5; ++t) {
      const int kk = dy * 5 + t;
      const unsigned short* tg = &sTG[(kk * 16 + ol) << 4];
      const u16x8 gmv = *(const u16x8*)tg;
      const u16x8 gav = *(const u16x8*)(tg + 8);
      const float a0 = bf2f(sAt[pxl][gl * 25 + kk]);
      const float a1 = bf2f(sAt[pxl + 1][gl * 25 + kk]);
      floatx2 a02, a12;
      a02[0] = a0; a02[1] = a0;
      a12[0] = a1; a12[1] = a1;
#pragma unroll
      for (int p = 0; p < 4; ++p) {
        floatx2 gm2, ga2, h0, h1;
        gm2[0] = bf2f(gmv[2 * p]);     gm2[1] = bf2f(gmv[2 * p + 1]);
        ga2[0] = bf2f(gav[2 * p]);     ga2[1] = bf2f(gav[2 * p + 1]);
        h0[0]  = bf2f(hv[t][2 * p]);   h0[1]  = bf2f(hv[t][2 * p + 1]);
        h1[0]  = bf2f(hv[t + 1][2 * p]); h1[1] = bf2f(hv[t + 1][2 * p + 1]);
        const floatx2 f0 = pk_fma(gm2, a02, ga2);
        const floatx2 f1 = pk_fma(gm2, a12, ga2);
        acc0[p] = pk_fma(h0, f0, acc0[p]);
        acc1[p] = pk_fma(h1, f1, acc1[p]);
      }
    }
  }

  u16x8 ov0, ov1;
#pragma unroll
  for (int p = 0; p < 4; ++p) {
    ov0[2 * p] = f2bf(acc0[p][0]); ov0[2 * p + 1] = f2bf(acc0[p][1]);
    ov1[2 * p] = f2bf(acc1[p][0]); ov1[2 * p + 1] = f2bf(acc1[p][1]);
  }
  *(u16x8*)(outp + (size_t)p0 * 384 + og * 8) = ov0;
  *(u16x8*)(outp + (size_t)(p0 + 1) * 384 + og * 8) = ov1;
}

// ---------------- Kernel D: post GEMM (hi/lo B frags from L2) ----------------
__global__ __launch_bounds__(256) void k_post_mfma(const unsigned short* __restrict__ outp,
                                                   const unsigned short* __restrict__ wpostf,
                                                   const float* __restrict__ b_post,
                                                   float* __restrict__ out) {
  __shared__ unsigned short sA[2][4096];
  const int tid = threadIdx.x;
  const int m0 = blockIdx.x * 128;
  const int yb = blockIdx.y;            // 0..2
  const int lane = tid & 63, wv = tid >> 6;
  const int wr = wv >> 1, wc = wv & 1;

  const floatx4 fz = {0.f, 0.f, 0.f, 0.f};
  floatx4 acc[4][4];
#pragma unroll
  for (int i = 0; i < 4; ++i)
#pragma unroll
    for (int j = 0; j < 4; ++j) acc[i][j] = fz;

  stage128x32(outp + (size_t)m0 * 384, 384, sA[0], tid);
  const unsigned short* bbase = wpostf + (size_t)(yb * 8 + wc * 4) * 6144 + lane * 8;

  int cur = 0;
#pragma unroll 1
  for (int s = 0; s < 12; ++s) {
    short8 bh[4], bl[4];
#pragma unroll
    for (int nf = 0; nf < 4; ++nf) {
      bh[nf] = *(const short8*)(bbase + (size_t)s * 512 + nf * 6144);
      bl[nf] = *(const short8*)(bbase + (size_t)s * 512 + nf * 6144 + 147456);
    }
    __syncthreads();
    if (s < 11) stage128x32(outp + (size_t)m0 * 384 + (s + 1) * 32, 384, sA[cur ^ 1], tid);
    short8 a[4];
#pragma unroll
    for (int mf = 0; mf < 4; ++mf)
      a[mf] = *(const short8*)&sA[cur][(wr * 64 + mf * 16 + (lane & 15)) * 32 + (lane >> 4) * 8];
#pragma unroll
    for (int mf = 0; mf < 4; ++mf)
#pragma unroll
      for (int nf = 0; nf < 4; ++nf) {
        acc[mf][nf] = __builtin_amdgcn_mfma_f32_16x16x32_bf16(a[mf], bh[nf], acc[mf][nf], 0, 0, 0);
        acc[mf][nf] = __builtin_amdgcn_mfma_f32_16x16x32_bf16(a[mf], bl[nf], acc[mf][nf], 0, 0, 0);
      }
    cur ^= 1;
  }

#pragma unroll
  for (int mf = 0; mf < 4; ++mf)
#pragma unroll
    for (int nf = 0; nf < 4; ++nf) {
      const int col = yb * 128 + wc * 64 + nf * 16 + (lane & 15);
      const float bias = b_post[col];
#pragma unroll
      for (int j = 0; j < 4; ++j) {
        const int row = m0 + wr * 64 + mf * 16 + (lane >> 4) * 4 + j;
        out[(size_t)row * 384 + col] = acc[mf][nf][j] + bias;
      }
    }
}

extern "C" void kernel_launch(void* const* d_in, const int* in_sizes, int n_in,
                              void* d_out, int out_size, void* d_ws, size_t ws_size,
                              hipStream_t stream) {
  const float* x      = (const float*)d_in[0];
  const float* w_pre  = (const float*)d_in[1];
  const float* w1     = (const float*)d_in[2];
  const float* b1     = (const float*)d_in[3];
  const float* w2     = (const float*)d_in[4];
  const float* b2     = (const float*)d_in[5];
  const float* gh     = (const float*)d_in[6];
  const float* w_post = (const float*)d_in[7];
  const float* b_post = (const float*)d_in[8];
  float* out = (float*)d_out;

  char* ws = (char*)d_ws;
  unsigned short* xb     = (unsigned short*)ws;
  unsigned short* hm     = (unsigned short*)ws;
  unsigned short* w1mp   = (unsigned short*)(ws + 25690112);
  unsigned short* w2f    = (unsigned short*)(ws + 25903104);    // 155,648 B
  unsigned short* outp   = (unsigned short*)ws;
  unsigned short* had    = (unsigned short*)(ws + 38535168);
  unsigned short* tgg    = (unsigned short*)(ws + 38535168);    // reuses dead `had`
  unsigned short* v      = (unsigned short*)(ws + 64225280);
  unsigned short* attn   = (unsigned short*)(ws + 102760448);
  unsigned short* wpbf   = (unsigned short*)(ws + 132866048);   // 688,128 B (56 groups)
  unsigned short* wpostf = (unsigned short*)(ws + 133554176);   // 589,824 B (hi+lo)

  k_cvt<<<dim3(2048), dim3(256), 0, stream>>>(x, xb, 19267584 / 8);
  k_wfrag<<<dim3(1344), dim3(256), 0, stream>>>(w_pre, wpbf, 344064);
  k_wpostf<<<dim3(1152), dim3(256), 0, stream>>>(w_post, wpostf);

  k_pre_qk<<<dim3(392, 2), dim3(256), 0, stream>>>(xb, wpbf, had);
  k_pre_v<<<dim3(392, 3), dim3(256), 0, stream>>>(xb, wpbf, v);

  // xb dead now; pack small weights into R0 slack
  k_w1mpack<<<dim3(416), dim3(256), 0, stream>>>(w1, w1mp);
  k_w2frag<<<dim3(304), dim3(256), 0, stream>>>(w2, w2f);

  k_conv_mfma<<<dim3(784, 2), dim3(256), 0, stream>>>(had, w1mp, b1, hm);
  // had dead now; tgg reuses its storage (outside R0)
  k_tggpack<<<dim3(75), dim3(256), 0, stream>>>(gh, tgg);
  k_1x1s<<<dim3(784), dim3(256), 0, stream>>>(hm, w2f, b2, attn);
  k_elsa<<<dim3(784, 3), dim3(512), 0, stream>>>(v, attn, tgg, outp);
  k_post_mfma<<<dim3(392, 3), dim3(256), 0, stream>>>(outp, wpostf, b_post, out);
}